// Round 6
// baseline (492.246 us; speedup 1.0000x reference)
//
#include <hip/hip_runtime.h>

// NeRF ray-marching renderer, MI355X — round 6.
//  - FIX: hierarchical coalesced scan for the 2^18-bucket counting sort
//    (round-5's single-block chunked scan was ~200us of divergent reads).
//  - f16 cell grid + v_dot2_f32_f16: cell = 4 voxels (y,z quad) x 4 channels
//    as half2 y-pairs (32 B). Bilerp per channel per x-plane = 2 fdot2.
//  - sort: 18-bit [entry cell 9b][exit cell 9b] key, one-pass counting sort.
//  - SPLIT=2 segments, depth-1 prefetch, XCD chunk swizzle.

constexpr int   kG     = 128;
constexpr int   kG3    = kG * kG * kG;
constexpr int   kSteps = 128;
constexpr int   kNRays = 262144;          // 2^18
constexpr int   kSB    = 1 << 18;         // sort buckets
constexpr float kBminX = -1.0f, kBminY = -0.5f, kBminZ = -1.0f;
constexpr float kBmaxX =  1.0f, kBmaxY =  0.5f, kBmaxZ =  1.0f;
constexpr float kSx = 63.5f, kSy = 127.0f, kSz = 63.5f;   // (G-1)/extent
constexpr float kMinNear = 0.05f;
constexpr float kTTh     = 1e-4f;

typedef _Float16 h2 __attribute__((ext_vector_type(2)));

__device__ __forceinline__ h2 as_h2(unsigned u) {
    union { unsigned u; h2 h; } c; c.u = u; return c.h;
}
__device__ __forceinline__ h2 mkh2(float a, float b) {
    h2 r; r.x = (_Float16)a; r.y = (_Float16)b; return r;
}
__device__ __forceinline__ float fdot2f(h2 a, h2 b, float c) {
#if __has_builtin(__builtin_amdgcn_fdot2)
    return __builtin_amdgcn_fdot2(a, b, c, false);
#else
    return (float)a.x * (float)b.x + (float)a.y * (float)b.y + c;
#endif
}

// ---------------- shared helpers ------------------------------------------
__device__ __forceinline__ void slabNearFar(
    float ox, float oy, float oz, float dx, float dy, float dz,
    float& near_, float& far_)
{
    float sdx = (fabsf(dx) < 1e-9f) ? 1e-9f : dx;
    float sdy = (fabsf(dy) < 1e-9f) ? 1e-9f : dy;
    float sdz = (fabsf(dz) < 1e-9f) ? 1e-9f : dz;
    float t1x = (kBminX - ox) / sdx, t2x = (kBmaxX - ox) / sdx;
    float t1y = (kBminY - oy) / sdy, t2y = (kBmaxY - oy) / sdy;
    float t1z = (kBminZ - oz) / sdz, t2z = (kBmaxZ - oz) / sdz;
    near_ = fmaxf(fmaxf(fminf(t1x, t2x), fminf(t1y, t2y)), fminf(t1z, t2z));
    far_  = fminf(fminf(fmaxf(t1x, t2x), fmaxf(t1y, t2y)), fmaxf(t1z, t2z));
    near_ = fmaxf(near_, kMinNear);
    far_  = fmaxf(far_, near_ + 1e-6f);
}

__device__ __forceinline__ void stepAddr(
    float near_, float dt, float ox, float oy, float oz,
    float dx, float dy, float dz, int s,
    int& cell, float& fx, float& fy, float& fz)
{
    float t  = fmaf((float)s + 0.5f, dt, near_);
    float px = fmaf(t, dx, ox), py = fmaf(t, dy, oy), pz = fmaf(t, dz, oz);
    float ux = fminf(fmaxf((px - kBminX) * kSx, 0.0f), 127.0f);
    float uy = fminf(fmaxf((py - kBminY) * kSy, 0.0f), 127.0f);
    float uz = fminf(fmaxf((pz - kBminZ) * kSz, 0.0f), 127.0f);
    float u0x = fminf(floorf(ux), 126.0f);
    float u0y = fminf(floorf(uy), 126.0f);
    float u0z = fminf(floorf(uz), 126.0f);
    fx = ux - u0x; fy = uy - u0y; fz = uz - u0z;
    cell = ((int)u0x << 14) + ((int)u0y << 7) + (int)u0z;
}

// ---------------- f16 cell repack -----------------------------------------
// voxel packed as uint2: lo = h(sig)|h(r)<<16, hi = h(g)|h(b)<<16
__device__ __forceinline__ uint2 packvox16(
    const float* __restrict__ sig, const float* __restrict__ rgb, int idx)
{
    unsigned s = (unsigned)__builtin_bit_cast(unsigned short, (_Float16)sig[idx]);
    unsigned r = (unsigned)__builtin_bit_cast(unsigned short, (_Float16)rgb[3*idx+0]);
    unsigned g = (unsigned)__builtin_bit_cast(unsigned short, (_Float16)rgb[3*idx+1]);
    unsigned b = (unsigned)__builtin_bit_cast(unsigned short, (_Float16)rgb[3*idx+2]);
    return make_uint2(s | (r << 16), g | (b << 16));
}

// Block = (ix, iy0): rows (iy0, iy0+1) -> LDS -> 128 cells of 32 B.
// Cell layout: Q0 = {s_y0pair, s_y1pair, r_y0pair, r_y1pair},
//              Q1 = {g_y0pair, g_y1pair, b_y0pair, b_y1pair}
// where *_yKpair = half2( v(yK,z0), v(yK,z1) ).
__global__ __launch_bounds__(128) void repack_f16_k(
    const float* __restrict__ sig, const float* __restrict__ rgb,
    uint4* __restrict__ out)
{
    __shared__ uint2 row[2][kG];
    int ix  = blockIdx.x >> 7;
    int iy0 = blockIdx.x & 127;
    int iy1 = min(iy0 + 1, 127);
    int z   = threadIdx.x;
    row[0][z] = packvox16(sig, rgb, (ix << 14) + (iy0 << 7) + z);
    row[1][z] = packvox16(sig, rgb, (ix << 14) + (iy1 << 7) + z);
    __syncthreads();
    int z1 = min(z + 1, 127);
    uint2 a = row[0][z], b = row[0][z1], c = row[1][z], d = row[1][z1];
    uint4 Q0 = make_uint4((a.x & 0xffffu) | (b.x << 16),
                          (c.x & 0xffffu) | (d.x << 16),
                          (a.x >> 16)     | (b.x & 0xffff0000u),
                          (c.x >> 16)     | (d.x & 0xffff0000u));
    uint4 Q1 = make_uint4((a.y & 0xffffu) | (b.y << 16),
                          (c.y & 0xffffu) | (d.y << 16),
                          (a.y >> 16)     | (b.y & 0xffff0000u),
                          (c.y >> 16)     | (d.y & 0xffff0000u));
    int cidx = (ix << 14) + (iy0 << 7) + z;
    out[(cidx << 1) + 0] = Q0;
    out[(cidx << 1) + 1] = Q1;
}

// ---------------- u8 quad repack (tier B) ---------------------------------
__device__ __forceinline__ unsigned packvox8(
    const float* __restrict__ sig, const float* __restrict__ rgb, int idx)
{
    unsigned s = (unsigned)__float2int_rn(fminf(fmaxf(sig[idx], 0.f), 1.f) * 255.f);
    unsigned r = (unsigned)__float2int_rn(fminf(fmaxf(rgb[3*idx+0], 0.f), 1.f) * 255.f);
    unsigned g = (unsigned)__float2int_rn(fminf(fmaxf(rgb[3*idx+1], 0.f), 1.f) * 255.f);
    unsigned b = (unsigned)__float2int_rn(fminf(fmaxf(rgb[3*idx+2], 0.f), 1.f) * 255.f);
    return s | (r << 8) | (g << 16) | (b << 24);
}

__global__ __launch_bounds__(128) void repack_u8_k(
    const float* __restrict__ sig, const float* __restrict__ rgb,
    uint4* __restrict__ out)
{
    __shared__ unsigned row[2][kG];
    int ix  = blockIdx.x >> 7;
    int iy0 = blockIdx.x & 127;
    int iy1 = min(iy0 + 1, 127);
    int z   = threadIdx.x;
    row[0][z] = packvox8(sig, rgb, (ix << 14) + (iy0 << 7) + z);
    row[1][z] = packvox8(sig, rgb, (ix << 14) + (iy1 << 7) + z);
    __syncthreads();
    int z1 = min(z + 1, 127);
    out[(ix << 14) + (iy0 << 7) + z] =
        make_uint4(row[0][z], row[0][z1], row[1][z], row[1][z1]);
}

// ---------------- counting sort: key, hist, hierarchical scan -------------
__global__ __launch_bounds__(256) void zero_k(int* __restrict__ p, int n)
{
    int i = blockIdx.x * 256 + threadIdx.x;
    if (i < n) p[i] = 0;
}

__device__ __forceinline__ int cell9(float x, float y, float z)
{
    int cx = min(7, max(0, (int)((x - kBminX) * 4.0f)));
    int cy = min(7, max(0, (int)((y - kBminY) * 8.0f)));
    int cz = min(7, max(0, (int)((z - kBminZ) * 4.0f)));
    return (cx << 6) | (cy << 3) | cz;
}

__device__ __forceinline__ int pathKey(
    const float* __restrict__ rays_o, const float* __restrict__ rays_d, int i)
{
    float ox = rays_o[3*i+0], oy = rays_o[3*i+1], oz = rays_o[3*i+2];
    float dx = rays_d[3*i+0], dy = rays_d[3*i+1], dz = rays_d[3*i+2];
    float near_, far_;
    slabNearFar(ox, oy, oz, dx, dy, dz, near_, far_);
    int ke = cell9(fmaf(near_, dx, ox), fmaf(near_, dy, oy), fmaf(near_, dz, oz));
    int kx = cell9(fmaf(far_,  dx, ox), fmaf(far_,  dy, oy), fmaf(far_,  dz, oz));
    return (ke << 9) | kx;
}

__global__ __launch_bounds__(256) void hist18_k(
    const float* __restrict__ rays_o, const float* __restrict__ rays_d,
    int* __restrict__ hist)
{
    int i = blockIdx.x * 256 + threadIdx.x;
    if (i >= kNRays) return;
    atomicAdd(&hist[pathKey(rays_o, rays_d, i)], 1);
}

// per-256-block exclusive scan; h[i] <- local exclusive, bsum[b] <- block total
__global__ __launch_bounds__(256) void scan_blk_k(
    int* __restrict__ h, int* __restrict__ bsum)
{
    __shared__ int tmp[256];
    int t = threadIdx.x;
    int i = blockIdx.x * 256 + t;
    int v = h[i];
    tmp[t] = v;
    __syncthreads();
    int x = v;
    for (int off = 1; off < 256; off <<= 1) {
        int y = (t >= off) ? tmp[t - off] : 0;
        __syncthreads();
        x += y;
        tmp[t] = x;
        __syncthreads();
    }
    h[i] = x - v;
    if (t == 255) bsum[blockIdx.x] = x;
}

// exclusive scan of 1024 block sums, in place, one block
__global__ __launch_bounds__(256) void scan_top_k(int* __restrict__ bsum)
{
    __shared__ int tmp[256];
    int t = threadIdx.x;
    int4 v = reinterpret_cast<int4*>(bsum)[t];
    int s = v.x + v.y + v.z + v.w;
    tmp[t] = s;
    __syncthreads();
    int x = s;
    for (int off = 1; off < 256; off <<= 1) {
        int y = (t >= off) ? tmp[t - off] : 0;
        __syncthreads();
        x += y;
        tmp[t] = x;
        __syncthreads();
    }
    int exc = x - s;
    reinterpret_cast<int4*>(bsum)[t] =
        make_int4(exc, exc + v.x, exc + v.x + v.y, exc + v.x + v.y + v.z);
}

// pos = bsum[key>>8] + atomicAdd(&h[key],1)  (h holds local exclusive prefix)
__global__ __launch_bounds__(256) void scatter18_k(
    const float* __restrict__ rays_o, const float* __restrict__ rays_d,
    int* __restrict__ h, const int* __restrict__ bsum, int* __restrict__ perm)
{
    int i = blockIdx.x * 256 + threadIdx.x;
    if (i >= kNRays) return;
    int key = pathKey(rays_o, rays_d, i);
    int pos = bsum[key >> 8] + atomicAdd(&h[key], 1);
    perm[pos] = i;
}

// ---------------- render, f16 dot2 path -----------------------------------
__global__ __launch_bounds__(256, 6) void render_f16_k(
    const float* __restrict__ rays_o, const float* __restrict__ rays_d,
    const uint4* __restrict__ grid2, const int* __restrict__ perm,
    float4* __restrict__ pRGBW, float* __restrict__ pT)
{
    int bid = blockIdx.x;                       // 2048 blocks
    int swz = (bid & 7) * 256 + (bid >> 3);     // bijective XCD chunk swizzle
    int j   = swz * 256 + (int)threadIdx.x;
    int seg = j >> 18;
    int sj  = j & (kNRays - 1);
    int ray = perm[sj];

    float ox = rays_o[3*ray+0], oy = rays_o[3*ray+1], oz = rays_o[3*ray+2];
    float dx = rays_d[3*ray+0], dy = rays_d[3*ray+1], dz = rays_d[3*ray+2];
    float near_, far_;
    slabNearFar(ox, oy, oz, dx, dy, dz, near_, far_);
    float dt = (far_ - near_) * (1.0f / (float)kSteps);

    const int nsteps = kSteps / 2;
    const int s0 = seg * nsteps;

    int c; float fx, fy, fz;
    stepAddr(near_, dt, ox, oy, oz, dx, dy, dz, s0, c, fx, fy, fz);
    uint4 a0 = grid2[(c << 1) + 0], a1 = grid2[(c << 1) + 1];
    uint4 b0 = grid2[(c << 1) + (1 << 15)], b1 = grid2[(c << 1) + (1 << 15) + 1];

    float T = 1.0f, wsum = 0.0f, ar = 0.0f, ag = 0.0f, ab = 0.0f;

    for (int s = 0; s < nsteps; ++s) {
        int cn; float nfx, nfy, nfz;
        int sn = s0 + min(s + 1, nsteps - 1);
        stepAddr(near_, dt, ox, oy, oz, dx, dy, dz, sn, cn, nfx, nfy, nfz);
        uint4 na0 = grid2[(cn << 1) + 0], na1 = grid2[(cn << 1) + 1];
        uint4 nb0 = grid2[(cn << 1) + (1 << 15)], nb1 = grid2[(cn << 1) + (1 << 15) + 1];

        float wz0 = 1.0f - fz, wy0 = 1.0f - fy;
        h2 wA = mkh2(wy0 * wz0, wy0 * fz);      // (w00, w01)
        h2 wB = mkh2(fy  * wz0, fy  * fz);      // (w10, w11)

        float sA = fdot2f(as_h2(a0.y), wB, fdot2f(as_h2(a0.x), wA, 0.0f));
        float rA = fdot2f(as_h2(a0.w), wB, fdot2f(as_h2(a0.z), wA, 0.0f));
        float gA = fdot2f(as_h2(a1.y), wB, fdot2f(as_h2(a1.x), wA, 0.0f));
        float bA = fdot2f(as_h2(a1.w), wB, fdot2f(as_h2(a1.z), wA, 0.0f));
        float sB = fdot2f(as_h2(b0.y), wB, fdot2f(as_h2(b0.x), wA, 0.0f));
        float rB = fdot2f(as_h2(b0.w), wB, fdot2f(as_h2(b0.z), wA, 0.0f));
        float gB = fdot2f(as_h2(b1.y), wB, fdot2f(as_h2(b1.x), wA, 0.0f));
        float bB = fdot2f(as_h2(b1.w), wB, fdot2f(as_h2(b1.z), wA, 0.0f));

        float sv = fmaf(fx, sB - sA, sA);
        float rv = fmaf(fx, rB - rA, rA);
        float gv = fmaf(fx, gB - gA, gA);
        float bv = fmaf(fx, bB - bA, bA);

        float sigr  = (sv > 0.01f) ? sv : 0.0f;
        float alpha = 1.0f - __expf(-sigr * dt);
        alpha = (T > kTTh) ? alpha : 0.0f;                  // reference gating
        float w = alpha * T;
        T *= (1.0f - alpha);
        wsum += w;
        ar = fmaf(w, rv, ar);
        ag = fmaf(w, gv, ag);
        ab = fmaf(w, bv, ab);

        a0 = na0; a1 = na1; b0 = nb0; b1 = nb1;
        fx = nfx; fy = nfy; fz = nfz;
    }

    pRGBW[j] = make_float4(ar, ag, ab, wsum);
    pT[j] = T;
}

// ---------------- render, u8 quad path (tier B) ---------------------------
#define UB0(u) ((float)((u) & 0xffu))
#define UB1(u) ((float)(((u) >> 8) & 0xffu))
#define UB2(u) ((float)(((u) >> 16) & 0xffu))
#define UB3(u) ((float)((u) >> 24))

__global__ __launch_bounds__(256, 8) void render_u8_k(
    const float* __restrict__ rays_o, const float* __restrict__ rays_d,
    const uint4* __restrict__ grid, const int* __restrict__ perm,
    float4* __restrict__ pRGBW, float* __restrict__ pT)
{
    int bid = blockIdx.x;
    int swz = (bid & 7) * 256 + (bid >> 3);
    int j   = swz * 256 + (int)threadIdx.x;
    int seg = j >> 18;
    int sj  = j & (kNRays - 1);
    int ray = perm[sj];

    float ox = rays_o[3*ray+0], oy = rays_o[3*ray+1], oz = rays_o[3*ray+2];
    float dx = rays_d[3*ray+0], dy = rays_d[3*ray+1], dz = rays_d[3*ray+2];
    float near_, far_;
    slabNearFar(ox, oy, oz, dx, dy, dz, near_, far_);
    float dt  = (far_ - near_) * (1.0f / (float)kSteps);
    float dtq = dt * (1.0f / 255.0f);

    const int nsteps = kSteps / 2;
    const int s0 = seg * nsteps;

    int c; float fx, fy, fz;
    stepAddr(near_, dt, ox, oy, oz, dx, dy, dz, s0, c, fx, fy, fz);
    uint4 q0 = grid[c], q1 = grid[c + (1 << 14)];

    float T = 1.0f, wsum = 0.0f, ar = 0.0f, ag = 0.0f, ab = 0.0f;

    for (int s = 0; s < nsteps; ++s) {
        int cn; float nfx, nfy, nfz;
        int sn = s0 + min(s + 1, nsteps - 1);
        stepAddr(near_, dt, ox, oy, oz, dx, dy, dz, sn, cn, nfx, nfy, nfz);
        uint4 m0 = grid[cn], m1 = grid[cn + (1 << 14)];

        float wz0 = 1.0f - fz, wy0 = 1.0f - fy;
        float w00 = wy0 * wz0, w01 = wy0 * fz, w10 = fy * wz0, w11 = fy * fz;

        float sA = w00*UB0(q0.x) + w01*UB0(q0.y) + w10*UB0(q0.z) + w11*UB0(q0.w);
        float sB = w00*UB0(q1.x) + w01*UB0(q1.y) + w10*UB0(q1.z) + w11*UB0(q1.w);
        float rA = w00*UB1(q0.x) + w01*UB1(q0.y) + w10*UB1(q0.z) + w11*UB1(q0.w);
        float rB = w00*UB1(q1.x) + w01*UB1(q1.y) + w10*UB1(q1.z) + w11*UB1(q1.w);
        float gA = w00*UB2(q0.x) + w01*UB2(q0.y) + w10*UB2(q0.z) + w11*UB2(q0.w);
        float gB = w00*UB2(q1.x) + w01*UB2(q1.y) + w10*UB2(q1.z) + w11*UB2(q1.w);
        float bA = w00*UB3(q0.x) + w01*UB3(q0.y) + w10*UB3(q0.z) + w11*UB3(q0.w);
        float bB = w00*UB3(q1.x) + w01*UB3(q1.y) + w10*UB3(q1.z) + w11*UB3(q1.w);

        float sv = fmaf(fx, sB - sA, sA);
        float rv = fmaf(fx, rB - rA, rA);
        float gv = fmaf(fx, gB - gA, gA);
        float bv = fmaf(fx, bB - bA, bA);

        float sigr  = (sv > 2.55f) ? sv : 0.0f;
        float alpha = 1.0f - __expf(-sigr * dtq);
        alpha = (T > kTTh) ? alpha : 0.0f;
        float w = alpha * T;
        T *= (1.0f - alpha);
        wsum += w;
        ar = fmaf(w, rv, ar);
        ag = fmaf(w, gv, ag);
        ab = fmaf(w, bv, ab);

        q0 = m0; q1 = m1; fx = nfx; fy = nfy; fz = nfz;
    }

    const float inv = 1.0f / 255.0f;
    pRGBW[j] = make_float4(ar * inv, ag * inv, ab * inv, wsum);
    pT[j] = T;
}

// ---------------- merge (SPLIT=2) -----------------------------------------
__global__ __launch_bounds__(256) void merge2_k(
    const float4* __restrict__ pRGBW, const float* __restrict__ pT,
    const int* __restrict__ perm, const float* __restrict__ bg,
    float* __restrict__ out)
{
    int k = blockIdx.x * 256 + threadIdx.x;
    if (k >= kNRays) return;
    float4 a = pRGBW[k];
    float4 b = pRGBW[k + kNRays];
    float T0 = pT[k];
    float ar = fmaf(T0, b.x, a.x), ag = fmaf(T0, b.y, a.y);
    float ab2 = fmaf(T0, b.z, a.z), ws = fmaf(T0, b.w, a.w);
    int ray = perm[k];
    float omw = 1.0f - ws;
    out[3 * ray + 0] = fminf(fmaxf(fmaf(omw, bg[0], ar), 0.0f), 1.0f);
    out[3 * ray + 1] = fminf(fmaxf(fmaf(omw, bg[1], ag), 0.0f), 1.0f);
    out[3 * ray + 2] = fminf(fmaxf(fmaf(omw, bg[2], ab2), 0.0f), 1.0f);
}

// ---------------- plain fallback ------------------------------------------
__global__ __launch_bounds__(256) void render_plain_k(
    const float* __restrict__ rays_o, const float* __restrict__ rays_d,
    const float* __restrict__ sgrid, const float* __restrict__ cgrid,
    const float* __restrict__ bg, float* __restrict__ out)
{
    int i = blockIdx.x * 256 + threadIdx.x;
    if (i >= kNRays) return;
    float ox = rays_o[3*i+0], oy = rays_o[3*i+1], oz = rays_o[3*i+2];
    float dx = rays_d[3*i+0], dy = rays_d[3*i+1], dz = rays_d[3*i+2];
    float near_, far_;
    slabNearFar(ox, oy, oz, dx, dy, dz, near_, far_);
    float dt = (far_ - near_) * (1.0f / (float)kSteps);
    float T = 1.0f, wsum = 0.0f, accr = 0.0f, accg = 0.0f, accb = 0.0f;
    for (int s = 0; s < kSteps; ++s) {
        int base; float fx, fy, fz;
        stepAddr(near_, dt, ox, oy, oz, dx, dy, dz, s, base, fx, fy, fz);
        float w0x = 1.0f - fx, w0y = 1.0f - fy, w0z = 1.0f - fz;
        float wa = w0x*w0y*w0z, wb = w0x*w0y*fz, wc = w0x*fy*w0z, wd = w0x*fy*fz;
        float we = fx*w0y*w0z,  wf = fx*w0y*fz,  wg = fx*fy*w0z,  wh = fx*fy*fz;
        int i000 = base, i001 = base + 1, i010 = base + kG, i011 = base + kG + 1;
        int i100 = base + kG*kG, i101 = i100 + 1, i110 = i100 + kG, i111 = i110 + 1;
        float sv = wa*sgrid[i000] + wb*sgrid[i001] + wc*sgrid[i010] + wd*sgrid[i011]
                 + we*sgrid[i100] + wf*sgrid[i101] + wg*sgrid[i110] + wh*sgrid[i111];
        float rv = wa*cgrid[3*i000+0] + wb*cgrid[3*i001+0] + wc*cgrid[3*i010+0] + wd*cgrid[3*i011+0]
                 + we*cgrid[3*i100+0] + wf*cgrid[3*i101+0] + wg*cgrid[3*i110+0] + wh*cgrid[3*i111+0];
        float gv = wa*cgrid[3*i000+1] + wb*cgrid[3*i001+1] + wc*cgrid[3*i010+1] + wd*cgrid[3*i011+1]
                 + we*cgrid[3*i100+1] + wf*cgrid[3*i101+1] + wg*cgrid[3*i110+1] + wh*cgrid[3*i111+1];
        float bv = wa*cgrid[3*i000+2] + wb*cgrid[3*i001+2] + wc*cgrid[3*i010+2] + wd*cgrid[3*i011+2]
                 + we*cgrid[3*i100+2] + wf*cgrid[3*i101+2] + wg*cgrid[3*i110+2] + wh*cgrid[3*i111+2];
        float sig = (sv > 0.01f) ? sv : 0.0f;
        float alpha = 1.0f - __expf(-sig * dt);
        float w = alpha * T;
        T *= (1.0f - alpha);
        wsum += w;
        accr = fmaf(w, rv, accr); accg = fmaf(w, gv, accg); accb = fmaf(w, bv, accb);
        if (T <= kTTh) break;
    }
    float omw = 1.0f - wsum;
    out[3 * i + 0] = fminf(fmaxf(fmaf(omw, bg[0], accr), 0.0f), 1.0f);
    out[3 * i + 1] = fminf(fmaxf(fmaf(omw, bg[1], accg), 0.0f), 1.0f);
    out[3 * i + 2] = fminf(fmaxf(fmaf(omw, bg[2], accb), 0.0f), 1.0f);
}

extern "C" void kernel_launch(void* const* d_in, const int* in_sizes, int n_in,
                              void* d_out, int out_size, void* d_ws, size_t ws_size,
                              hipStream_t stream)
{
    const float* rays_o = (const float*)d_in[0];
    const float* rays_d = (const float*)d_in[1];
    const float* sgrid  = (const float*)d_in[2];
    const float* cgrid  = (const float*)d_in[3];
    const float* bg     = (const float*)d_in[4];
    float* out = (float*)d_out;

    const int RB_BLK = kNRays / 256;   // 1024

    // Tier A (f16 grid): grid2 64 MiB | hist 1 MiB | bsum 4 KiB | perm 1 MiB
    //                    | rgbw 8 MiB | pT 2 MiB  ~= 76 MiB
    size_t a_grid = 0;
    size_t a_hist = a_grid + (size_t)(2 * kG3) * sizeof(uint4);
    size_t a_bsum = a_hist + (size_t)kSB * sizeof(int);
    size_t a_perm = a_bsum + (size_t)1024 * sizeof(int);
    size_t a_rgbw = a_perm + (size_t)kNRays * sizeof(int);
    size_t a_pt   = a_rgbw + (size_t)(2 * kNRays) * sizeof(float4);
    size_t needA  = a_pt   + (size_t)(2 * kNRays) * sizeof(float);

    // Tier B (u8 grid): 32 MiB grid, same rest ~= 44 MiB
    size_t b_grid = 0;
    size_t b_hist = b_grid + (size_t)kG3 * sizeof(uint4);
    size_t b_bsum = b_hist + (size_t)kSB * sizeof(int);
    size_t b_perm = b_bsum + (size_t)1024 * sizeof(int);
    size_t b_rgbw = b_perm + (size_t)kNRays * sizeof(int);
    size_t b_pt   = b_rgbw + (size_t)(2 * kNRays) * sizeof(float4);
    size_t needB  = b_pt   + (size_t)(2 * kNRays) * sizeof(float);

    if (ws_size >= needA) {
        char* ws = (char*)d_ws;
        uint4*  grid2 = (uint4*)(ws + a_grid);
        int*    hist  = (int*)(ws + a_hist);
        int*    bsum  = (int*)(ws + a_bsum);
        int*    perm  = (int*)(ws + a_perm);
        float4* rgbw  = (float4*)(ws + a_rgbw);
        float*  pt    = (float*)(ws + a_pt);

        repack_f16_k<<<kG * kG, 128, 0, stream>>>(sgrid, cgrid, grid2);
        zero_k<<<kSB / 256, 256, 0, stream>>>(hist, kSB);
        hist18_k<<<RB_BLK, 256, 0, stream>>>(rays_o, rays_d, hist);
        scan_blk_k<<<kSB / 256, 256, 0, stream>>>(hist, bsum);
        scan_top_k<<<1, 256, 0, stream>>>(bsum);
        scatter18_k<<<RB_BLK, 256, 0, stream>>>(rays_o, rays_d, hist, bsum, perm);
        render_f16_k<<<2 * kNRays / 256, 256, 0, stream>>>(
            rays_o, rays_d, grid2, perm, rgbw, pt);
        merge2_k<<<RB_BLK, 256, 0, stream>>>(rgbw, pt, perm, bg, out);
    } else if (ws_size >= needB) {
        char* ws = (char*)d_ws;
        uint4*  grid = (uint4*)(ws + b_grid);
        int*    hist = (int*)(ws + b_hist);
        int*    bsum = (int*)(ws + b_bsum);
        int*    perm = (int*)(ws + b_perm);
        float4* rgbw = (float4*)(ws + b_rgbw);
        float*  pt   = (float*)(ws + b_pt);

        repack_u8_k<<<kG * kG, 128, 0, stream>>>(sgrid, cgrid, grid);
        zero_k<<<kSB / 256, 256, 0, stream>>>(hist, kSB);
        hist18_k<<<RB_BLK, 256, 0, stream>>>(rays_o, rays_d, hist);
        scan_blk_k<<<kSB / 256, 256, 0, stream>>>(hist, bsum);
        scan_top_k<<<1, 256, 0, stream>>>(bsum);
        scatter18_k<<<RB_BLK, 256, 0, stream>>>(rays_o, rays_d, hist, bsum, perm);
        render_u8_k<<<2 * kNRays / 256, 256, 0, stream>>>(
            rays_o, rays_d, grid, perm, rgbw, pt);
        merge2_k<<<RB_BLK, 256, 0, stream>>>(rgbw, pt, perm, bg, out);
    } else {
        render_plain_k<<<RB_BLK, 256, 0, stream>>>(
            rays_o, rays_d, sgrid, cgrid, bg, out);
    }
}

// Round 7
// 345.758 us; speedup vs baseline: 1.4237x; 1.4237x over previous
//
#include <hip/hip_runtime.h>

// NeRF ray-marching renderer, MI355X — round 7.
// Best-of-rounds assembly:
//  - u8 quad-cell grid, 2 gather requests/step  (round 3/5: request count is
//    the bottleneck; f16's 4 req/step regressed 202->350us).
//  - 18-bit entry/exit path sort, hierarchical coalesced scan (round 6 fix).
//  - SPLIT=2, 2-deep prefetch, XCD chunk swizzle (round 5: FETCH 43MB).
//  - Incremental grid-coordinate stepping (u = u0 + s*du): ~8 VALU/step saved.
//  - hipMemsetAsync for hist zero (fewer dispatches).

constexpr int   kG     = 128;
constexpr int   kG3    = kG * kG * kG;
constexpr int   kSteps = 128;
constexpr int   kNRays = 262144;          // 2^18
constexpr int   kSB    = 1 << 18;         // sort buckets
constexpr float kBminX = -1.0f, kBminY = -0.5f, kBminZ = -1.0f;
constexpr float kBmaxX =  1.0f, kBmaxY =  0.5f, kBmaxZ =  1.0f;
constexpr float kSx = 63.5f, kSy = 127.0f, kSz = 63.5f;   // (G-1)/extent
constexpr float kMinNear = 0.05f;
constexpr float kTTh     = 1e-4f;

// ---------------- shared helpers ------------------------------------------
__device__ __forceinline__ void slabNearFar(
    float ox, float oy, float oz, float dx, float dy, float dz,
    float& near_, float& far_)
{
    float sdx = (fabsf(dx) < 1e-9f) ? 1e-9f : dx;
    float sdy = (fabsf(dy) < 1e-9f) ? 1e-9f : dy;
    float sdz = (fabsf(dz) < 1e-9f) ? 1e-9f : dz;
    float t1x = (kBminX - ox) / sdx, t2x = (kBmaxX - ox) / sdx;
    float t1y = (kBminY - oy) / sdy, t2y = (kBmaxY - oy) / sdy;
    float t1z = (kBminZ - oz) / sdz, t2z = (kBmaxZ - oz) / sdz;
    near_ = fmaxf(fmaxf(fminf(t1x, t2x), fminf(t1y, t2y)), fminf(t1z, t2z));
    far_  = fminf(fminf(fmaxf(t1x, t2x), fmaxf(t1y, t2y)), fmaxf(t1z, t2z));
    near_ = fmaxf(near_, kMinNear);
    far_  = fmaxf(far_, near_ + 1e-6f);
}

// grid coords are linear in step index: u(s) = u0 + s*du (per axis).
__device__ __forceinline__ void cellOf(
    float u0x, float u0y, float u0z, float dux, float duy, float duz,
    float sf, int& cell, float& fx, float& fy, float& fz)
{
    float ux = fminf(fmaxf(fmaf(sf, dux, u0x), 0.0f), 127.0f);
    float uy = fminf(fmaxf(fmaf(sf, duy, u0y), 0.0f), 127.0f);
    float uz = fminf(fmaxf(fmaf(sf, duz, u0z), 0.0f), 127.0f);
    float cx = fminf(floorf(ux), 126.0f);
    float cy = fminf(floorf(uy), 126.0f);
    float cz = fminf(floorf(uz), 126.0f);
    fx = ux - cx; fy = uy - cy; fz = uz - cz;
    cell = ((int)cx << 14) + ((int)cy << 7) + (int)cz;
}

// ---------------- u8 quad repack (LDS-coalesced) --------------------------
__device__ __forceinline__ unsigned packvox8(
    const float* __restrict__ sig, const float* __restrict__ rgb, int idx)
{
    unsigned s = (unsigned)__float2int_rn(fminf(fmaxf(sig[idx], 0.f), 1.f) * 255.f);
    unsigned r = (unsigned)__float2int_rn(fminf(fmaxf(rgb[3*idx+0], 0.f), 1.f) * 255.f);
    unsigned g = (unsigned)__float2int_rn(fminf(fmaxf(rgb[3*idx+1], 0.f), 1.f) * 255.f);
    unsigned b = (unsigned)__float2int_rn(fminf(fmaxf(rgb[3*idx+2], 0.f), 1.f) * 255.f);
    return s | (r << 8) | (g << 16) | (b << 24);
}

__global__ __launch_bounds__(128) void repack_u8_k(
    const float* __restrict__ sig, const float* __restrict__ rgb,
    uint4* __restrict__ out)
{
    __shared__ unsigned row[2][kG];
    int ix  = blockIdx.x >> 7;
    int iy0 = blockIdx.x & 127;
    int iy1 = min(iy0 + 1, 127);
    int z   = threadIdx.x;
    row[0][z] = packvox8(sig, rgb, (ix << 14) + (iy0 << 7) + z);
    row[1][z] = packvox8(sig, rgb, (ix << 14) + (iy1 << 7) + z);
    __syncthreads();
    int z1 = min(z + 1, 127);
    out[(ix << 14) + (iy0 << 7) + z] =
        make_uint4(row[0][z], row[0][z1], row[1][z], row[1][z1]);
}

// ---------------- counting sort -------------------------------------------
__device__ __forceinline__ int cell9(float x, float y, float z)
{
    int cx = min(7, max(0, (int)((x - kBminX) * 4.0f)));
    int cy = min(7, max(0, (int)((y - kBminY) * 8.0f)));
    int cz = min(7, max(0, (int)((z - kBminZ) * 4.0f)));
    return (cx << 6) | (cy << 3) | cz;
}

__device__ __forceinline__ int pathKey(
    const float* __restrict__ rays_o, const float* __restrict__ rays_d, int i)
{
    float ox = rays_o[3*i+0], oy = rays_o[3*i+1], oz = rays_o[3*i+2];
    float dx = rays_d[3*i+0], dy = rays_d[3*i+1], dz = rays_d[3*i+2];
    float near_, far_;
    slabNearFar(ox, oy, oz, dx, dy, dz, near_, far_);
    int ke = cell9(fmaf(near_, dx, ox), fmaf(near_, dy, oy), fmaf(near_, dz, oz));
    int kx = cell9(fmaf(far_,  dx, ox), fmaf(far_,  dy, oy), fmaf(far_,  dz, oz));
    return (ke << 9) | kx;
}

__global__ __launch_bounds__(256) void hist18_k(
    const float* __restrict__ rays_o, const float* __restrict__ rays_d,
    int* __restrict__ hist)
{
    int i = blockIdx.x * 256 + threadIdx.x;
    if (i >= kNRays) return;
    atomicAdd(&hist[pathKey(rays_o, rays_d, i)], 1);
}

// per-256-block exclusive scan; h[i] <- local exclusive, bsum[b] <- block total
__global__ __launch_bounds__(256) void scan_blk_k(
    int* __restrict__ h, int* __restrict__ bsum)
{
    __shared__ int tmp[256];
    int t = threadIdx.x;
    int i = blockIdx.x * 256 + t;
    int v = h[i];
    tmp[t] = v;
    __syncthreads();
    int x = v;
    for (int off = 1; off < 256; off <<= 1) {
        int y = (t >= off) ? tmp[t - off] : 0;
        __syncthreads();
        x += y;
        tmp[t] = x;
        __syncthreads();
    }
    h[i] = x - v;
    if (t == 255) bsum[blockIdx.x] = x;
}

// exclusive scan of 1024 block sums, in place, one block
__global__ __launch_bounds__(256) void scan_top_k(int* __restrict__ bsum)
{
    __shared__ int tmp[256];
    int t = threadIdx.x;
    int4 v = reinterpret_cast<int4*>(bsum)[t];
    int s = v.x + v.y + v.z + v.w;
    tmp[t] = s;
    __syncthreads();
    int x = s;
    for (int off = 1; off < 256; off <<= 1) {
        int y = (t >= off) ? tmp[t - off] : 0;
        __syncthreads();
        x += y;
        tmp[t] = x;
        __syncthreads();
    }
    int exc = x - s;
    reinterpret_cast<int4*>(bsum)[t] =
        make_int4(exc, exc + v.x, exc + v.x + v.y, exc + v.x + v.y + v.z);
}

__global__ __launch_bounds__(256) void scatter18_k(
    const float* __restrict__ rays_o, const float* __restrict__ rays_d,
    int* __restrict__ h, const int* __restrict__ bsum, int* __restrict__ perm)
{
    int i = blockIdx.x * 256 + threadIdx.x;
    if (i >= kNRays) return;
    int key = pathKey(rays_o, rays_d, i);
    int pos = bsum[key >> 8] + atomicAdd(&h[key], 1);
    perm[pos] = i;
}

// ---------------- render: u8 quad, SPLIT=2, 2-deep prefetch ---------------
#define UB0(u) ((float)((u) & 0xffu))
#define UB1(u) ((float)(((u) >> 8) & 0xffu))
#define UB2(u) ((float)(((u) >> 16) & 0xffu))
#define UB3(u) ((float)((u) >> 24))

__global__ __launch_bounds__(256, 8) void render_u8_k(
    const float* __restrict__ rays_o, const float* __restrict__ rays_d,
    const uint4* __restrict__ grid, const int* __restrict__ perm,
    float4* __restrict__ pRGBW, float* __restrict__ pT)
{
    int bid = blockIdx.x;                       // 2048 blocks
    int swz = (bid & 7) * 256 + (bid >> 3);     // bijective XCD chunk swizzle
    int j   = swz * 256 + (int)threadIdx.x;
    int seg = j >> 18;
    int sj  = j & (kNRays - 1);
    int ray = perm[sj];

    float ox = rays_o[3*ray+0], oy = rays_o[3*ray+1], oz = rays_o[3*ray+2];
    float dx = rays_d[3*ray+0], dy = rays_d[3*ray+1], dz = rays_d[3*ray+2];
    float near_, far_;
    slabNearFar(ox, oy, oz, dx, dy, dz, near_, far_);
    float dt  = (far_ - near_) * (1.0f / (float)kSteps);
    float dtq = dt * (1.0f / 255.0f);

    const int nsteps = kSteps / 2;

    // grid coords linear in global step sg: u = u0 + sg*du, sg = seg*64 + s
    float t0  = fmaf(0.5f, dt, near_);
    float u0x = (fmaf(t0, dx, ox) - kBminX) * kSx;
    float u0y = (fmaf(t0, dy, oy) - kBminY) * kSy;
    float u0z = (fmaf(t0, dz, oz) - kBminZ) * kSz;
    float dux = dx * dt * kSx, duy = dy * dt * kSy, duz = dz * dt * kSz;
    // fold segment offset into the base
    float sb = (float)(seg * nsteps);
    u0x = fmaf(sb, dux, u0x); u0y = fmaf(sb, duy, u0y); u0z = fmaf(sb, duz, u0z);

    int c;
    float f0x, f0y, f0z, f1x, f1y, f1z, f2x, f2y, f2z;
    cellOf(u0x, u0y, u0z, dux, duy, duz, 0.0f, c, f0x, f0y, f0z);
    uint4 q0 = grid[c], q1 = grid[c + (1 << 14)];
    cellOf(u0x, u0y, u0z, dux, duy, duz, 1.0f, c, f1x, f1y, f1z);
    uint4 m0 = grid[c], m1 = grid[c + (1 << 14)];

    float T = 1.0f, wsum = 0.0f, ar = 0.0f, ag = 0.0f, ab = 0.0f;

    for (int s = 0; s < nsteps; ++s) {
        float sn = (float)min(s + 2, nsteps - 1);
        cellOf(u0x, u0y, u0z, dux, duy, duz, sn, c, f2x, f2y, f2z);
        uint4 n0 = grid[c], n1 = grid[c + (1 << 14)];

        float wz0 = 1.0f - f0z, wy0 = 1.0f - f0y;
        float w00 = wy0 * wz0, w01 = wy0 * f0z, w10 = f0y * wz0, w11 = f0y * f0z;

        float sA = w00*UB0(q0.x) + w01*UB0(q0.y) + w10*UB0(q0.z) + w11*UB0(q0.w);
        float sB = w00*UB0(q1.x) + w01*UB0(q1.y) + w10*UB0(q1.z) + w11*UB0(q1.w);
        float rA = w00*UB1(q0.x) + w01*UB1(q0.y) + w10*UB1(q0.z) + w11*UB1(q0.w);
        float rB = w00*UB1(q1.x) + w01*UB1(q1.y) + w10*UB1(q1.z) + w11*UB1(q1.w);
        float gA = w00*UB2(q0.x) + w01*UB2(q0.y) + w10*UB2(q0.z) + w11*UB2(q0.w);
        float gB = w00*UB2(q1.x) + w01*UB2(q1.y) + w10*UB2(q1.z) + w11*UB2(q1.w);
        float bA = w00*UB3(q0.x) + w01*UB3(q0.y) + w10*UB3(q0.z) + w11*UB3(q0.w);
        float bB = w00*UB3(q1.x) + w01*UB3(q1.y) + w10*UB3(q1.z) + w11*UB3(q1.w);

        float sv = fmaf(f0x, sB - sA, sA);      // raw counts in [0,255]
        float rv = fmaf(f0x, rB - rA, rA);
        float gv = fmaf(f0x, gB - gA, gA);
        float bv = fmaf(f0x, bB - bA, bA);

        float sigr  = (sv > 2.55f) ? sv : 0.0f;            // sigma > 0.01
        float alpha = 1.0f - __expf(-sigr * dtq);
        alpha = (T > kTTh) ? alpha : 0.0f;                  // reference gating
        float w = alpha * T;
        T *= (1.0f - alpha);
        wsum += w;
        ar = fmaf(w, rv, ar);
        ag = fmaf(w, gv, ag);
        ab = fmaf(w, bv, ab);

        q0 = m0; q1 = m1; m0 = n0; m1 = n1;
        f0x = f1x; f0y = f1y; f0z = f1z;
        f1x = f2x; f1y = f2y; f1z = f2z;
    }

    const float inv = 1.0f / 255.0f;
    pRGBW[j] = make_float4(ar * inv, ag * inv, ab * inv, wsum);
    pT[j] = T;
}

// ---------------- merge (SPLIT=2) -----------------------------------------
__global__ __launch_bounds__(256) void merge2_k(
    const float4* __restrict__ pRGBW, const float* __restrict__ pT,
    const int* __restrict__ perm, const float* __restrict__ bg,
    float* __restrict__ out)
{
    int k = blockIdx.x * 256 + threadIdx.x;
    if (k >= kNRays) return;
    float4 a = pRGBW[k];
    float4 b = pRGBW[k + kNRays];
    float T0 = pT[k];
    float ar = fmaf(T0, b.x, a.x), ag = fmaf(T0, b.y, a.y);
    float ab2 = fmaf(T0, b.z, a.z), ws = fmaf(T0, b.w, a.w);
    int ray = perm[k];
    float omw = 1.0f - ws;
    out[3 * ray + 0] = fminf(fmaxf(fmaf(omw, bg[0], ar), 0.0f), 1.0f);
    out[3 * ray + 1] = fminf(fmaxf(fmaf(omw, bg[1], ag), 0.0f), 1.0f);
    out[3 * ray + 2] = fminf(fmaxf(fmaf(omw, bg[2], ab2), 0.0f), 1.0f);
}

// ---------------- plain fallback ------------------------------------------
__global__ __launch_bounds__(256) void render_plain_k(
    const float* __restrict__ rays_o, const float* __restrict__ rays_d,
    const float* __restrict__ sgrid, const float* __restrict__ cgrid,
    const float* __restrict__ bg, float* __restrict__ out)
{
    int i = blockIdx.x * 256 + threadIdx.x;
    if (i >= kNRays) return;
    float ox = rays_o[3*i+0], oy = rays_o[3*i+1], oz = rays_o[3*i+2];
    float dx = rays_d[3*i+0], dy = rays_d[3*i+1], dz = rays_d[3*i+2];
    float near_, far_;
    slabNearFar(ox, oy, oz, dx, dy, dz, near_, far_);
    float dt = (far_ - near_) * (1.0f / (float)kSteps);
    float t0  = fmaf(0.5f, dt, near_);
    float u0x = (fmaf(t0, dx, ox) - kBminX) * kSx;
    float u0y = (fmaf(t0, dy, oy) - kBminY) * kSy;
    float u0z = (fmaf(t0, dz, oz) - kBminZ) * kSz;
    float dux = dx * dt * kSx, duy = dy * dt * kSy, duz = dz * dt * kSz;
    float T = 1.0f, wsum = 0.0f, accr = 0.0f, accg = 0.0f, accb = 0.0f;
    for (int s = 0; s < kSteps; ++s) {
        int base; float fx, fy, fz;
        cellOf(u0x, u0y, u0z, dux, duy, duz, (float)s, base, fx, fy, fz);
        float w0x = 1.0f - fx, w0y = 1.0f - fy, w0z = 1.0f - fz;
        float wa = w0x*w0y*w0z, wb = w0x*w0y*fz, wc = w0x*fy*w0z, wd = w0x*fy*fz;
        float we = fx*w0y*w0z,  wf = fx*w0y*fz,  wg = fx*fy*w0z,  wh = fx*fy*fz;
        int i000 = base, i001 = base + 1, i010 = base + kG, i011 = base + kG + 1;
        int i100 = base + kG*kG, i101 = i100 + 1, i110 = i100 + kG, i111 = i110 + 1;
        float sv = wa*sgrid[i000] + wb*sgrid[i001] + wc*sgrid[i010] + wd*sgrid[i011]
                 + we*sgrid[i100] + wf*sgrid[i101] + wg*sgrid[i110] + wh*sgrid[i111];
        float rv = wa*cgrid[3*i000+0] + wb*cgrid[3*i001+0] + wc*cgrid[3*i010+0] + wd*cgrid[3*i011+0]
                 + we*cgrid[3*i100+0] + wf*cgrid[3*i101+0] + wg*cgrid[3*i110+0] + wh*cgrid[3*i111+0];
        float gv = wa*cgrid[3*i000+1] + wb*cgrid[3*i001+1] + wc*cgrid[3*i010+1] + wd*cgrid[3*i011+1]
                 + we*cgrid[3*i100+1] + wf*cgrid[3*i101+1] + wg*cgrid[3*i110+1] + wh*cgrid[3*i111+1];
        float bv = wa*cgrid[3*i000+2] + wb*cgrid[3*i001+2] + wc*cgrid[3*i010+2] + wd*cgrid[3*i011+2]
                 + we*cgrid[3*i100+2] + wf*cgrid[3*i101+2] + wg*cgrid[3*i110+2] + wh*cgrid[3*i111+2];
        float sig = (sv > 0.01f) ? sv : 0.0f;
        float alpha = 1.0f - __expf(-sig * dt);
        float w = alpha * T;
        T *= (1.0f - alpha);
        wsum += w;
        accr = fmaf(w, rv, accr); accg = fmaf(w, gv, accg); accb = fmaf(w, bv, accb);
        if (T <= kTTh) break;
    }
    float omw = 1.0f - wsum;
    out[3 * i + 0] = fminf(fmaxf(fmaf(omw, bg[0], accr), 0.0f), 1.0f);
    out[3 * i + 1] = fminf(fmaxf(fmaf(omw, bg[1], accg), 0.0f), 1.0f);
    out[3 * i + 2] = fminf(fmaxf(fmaf(omw, bg[2], accb), 0.0f), 1.0f);
}

extern "C" void kernel_launch(void* const* d_in, const int* in_sizes, int n_in,
                              void* d_out, int out_size, void* d_ws, size_t ws_size,
                              hipStream_t stream)
{
    const float* rays_o = (const float*)d_in[0];
    const float* rays_d = (const float*)d_in[1];
    const float* sgrid  = (const float*)d_in[2];
    const float* cgrid  = (const float*)d_in[3];
    const float* bg     = (const float*)d_in[4];
    float* out = (float*)d_out;

    const int RB_BLK = kNRays / 256;   // 1024

    // Tier A: grid 32MiB | hist 1MiB | bsum 4KiB | perm 1MiB | rgbw 8MiB | pt 2MiB
    size_t a_grid = 0;
    size_t a_hist = a_grid + (size_t)kG3 * sizeof(uint4);
    size_t a_bsum = a_hist + (size_t)kSB * sizeof(int);
    size_t a_perm = a_bsum + (size_t)1024 * sizeof(int);
    size_t a_rgbw = a_perm + (size_t)kNRays * sizeof(int);
    size_t a_pt   = a_rgbw + (size_t)(2 * kNRays) * sizeof(float4);
    size_t needA  = a_pt   + (size_t)(2 * kNRays) * sizeof(float);

    if (ws_size >= needA) {
        char* ws = (char*)d_ws;
        uint4*  grid = (uint4*)(ws + a_grid);
        int*    hist = (int*)(ws + a_hist);
        int*    bsum = (int*)(ws + a_bsum);
        int*    perm = (int*)(ws + a_perm);
        float4* rgbw = (float4*)(ws + a_rgbw);
        float*  pt   = (float*)(ws + a_pt);

        repack_u8_k<<<kG * kG, 128, 0, stream>>>(sgrid, cgrid, grid);
        hipMemsetAsync(hist, 0, (size_t)kSB * sizeof(int), stream);
        hist18_k<<<RB_BLK, 256, 0, stream>>>(rays_o, rays_d, hist);
        scan_blk_k<<<kSB / 256, 256, 0, stream>>>(hist, bsum);
        scan_top_k<<<1, 256, 0, stream>>>(bsum);
        scatter18_k<<<RB_BLK, 256, 0, stream>>>(rays_o, rays_d, hist, bsum, perm);
        render_u8_k<<<2 * kNRays / 256, 256, 0, stream>>>(
            rays_o, rays_d, grid, perm, rgbw, pt);
        merge2_k<<<RB_BLK, 256, 0, stream>>>(rgbw, pt, perm, bg, out);
    } else {
        render_plain_k<<<RB_BLK, 256, 0, stream>>>(
            rays_o, rays_d, sgrid, cgrid, bg, out);
    }
}

// Round 8
// 334.477 us; speedup vs baseline: 1.4717x; 1.0337x over previous
//
#include <hip/hip_runtime.h>

// NeRF ray-marching renderer, MI355X — round 8.
//  - Corner-major u8 cells: cell(x,y,z) = uint4 { sigma4, r4, g4, b4 } where
//    each u32 holds the 4 (y,z)-quad corners as bytes -> bilerp per channel
//    per x-plane = ONE v_dot4_u32_u8 (u8 weights summing to 255).
//  - Fused merge: block = 256 rays x 2 segments (512 thr); seg1 partial via
//    LDS; seg0 composites + writes out. No merge kernel, no partial arrays.
//  - Pre-gathered sorted rays (so4/sd4) -> coalesced ray reads in render.
//  - 18-bit entry/exit path sort, hierarchical scan, XCD chunk swizzle,
//    2-deep prefetch (round 5/7 proven parts).

constexpr int   kG     = 128;
constexpr int   kG3    = kG * kG * kG;
constexpr int   kSteps = 128;
constexpr int   kNRays = 262144;          // 2^18
constexpr int   kSB    = 1 << 18;         // sort buckets
constexpr float kBminX = -1.0f, kBminY = -0.5f, kBminZ = -1.0f;
constexpr float kBmaxX =  1.0f, kBmaxY =  0.5f, kBmaxZ =  1.0f;
constexpr float kSx = 63.5f, kSy = 127.0f, kSz = 63.5f;   // (G-1)/extent
constexpr float kMinNear = 0.05f;
constexpr float kTTh     = 1e-4f;

#if __has_builtin(__builtin_amdgcn_udot4)
#define USE_UDOT4 1
constexpr float kScale  = 65025.0f;       // 255 (value) * 255 (weight)
#else
#define USE_UDOT4 0
constexpr float kScale  = 255.0f;
#endif
constexpr float kInvScale = 1.0f / kScale;
constexpr float kSigThr   = 0.01f * kScale;

// ---------------- shared helpers ------------------------------------------
__device__ __forceinline__ void slabNearFar(
    float ox, float oy, float oz, float dx, float dy, float dz,
    float& near_, float& far_)
{
    float sdx = (fabsf(dx) < 1e-9f) ? 1e-9f : dx;
    float sdy = (fabsf(dy) < 1e-9f) ? 1e-9f : dy;
    float sdz = (fabsf(dz) < 1e-9f) ? 1e-9f : dz;
    float t1x = (kBminX - ox) / sdx, t2x = (kBmaxX - ox) / sdx;
    float t1y = (kBminY - oy) / sdy, t2y = (kBmaxY - oy) / sdy;
    float t1z = (kBminZ - oz) / sdz, t2z = (kBmaxZ - oz) / sdz;
    near_ = fmaxf(fmaxf(fminf(t1x, t2x), fminf(t1y, t2y)), fminf(t1z, t2z));
    far_  = fminf(fminf(fmaxf(t1x, t2x), fmaxf(t1y, t2y)), fmaxf(t1z, t2z));
    near_ = fmaxf(near_, kMinNear);
    far_  = fmaxf(far_, near_ + 1e-6f);
}

// grid coords linear in step index: u(s) = u0 + s*du (per axis)
__device__ __forceinline__ void cellOf(
    float u0x, float u0y, float u0z, float dux, float duy, float duz,
    float sf, int& cell, float& fx, float& fy, float& fz)
{
    float ux = fminf(fmaxf(fmaf(sf, dux, u0x), 0.0f), 127.0f);
    float uy = fminf(fmaxf(fmaf(sf, duy, u0y), 0.0f), 127.0f);
    float uz = fminf(fmaxf(fmaf(sf, duz, u0z), 0.0f), 127.0f);
    float cx = fminf(floorf(ux), 126.0f);
    float cy = fminf(floorf(uy), 126.0f);
    float cz = fminf(floorf(uz), 126.0f);
    fx = ux - cx; fy = uy - cy; fz = uz - cz;
    cell = ((int)cx << 14) + ((int)cy << 7) + (int)cz;
}

// ---------------- corner-major u8 repack (LDS-coalesced) ------------------
__device__ __forceinline__ unsigned packvox8(
    const float* __restrict__ sig, const float* __restrict__ rgb, int idx)
{
    unsigned s = (unsigned)__float2int_rn(fminf(fmaxf(sig[idx], 0.f), 1.f) * 255.f);
    unsigned r = (unsigned)__float2int_rn(fminf(fmaxf(rgb[3*idx+0], 0.f), 1.f) * 255.f);
    unsigned g = (unsigned)__float2int_rn(fminf(fmaxf(rgb[3*idx+1], 0.f), 1.f) * 255.f);
    unsigned b = (unsigned)__float2int_rn(fminf(fmaxf(rgb[3*idx+2], 0.f), 1.f) * 255.f);
    return s | (r << 8) | (g << 16) | (b << 24);
}

// Block = (ix, iy0). Cell corners: byte0=(y0,z0) byte1=(y0,z1) byte2=(y1,z0)
// byte3=(y1,z1) per channel.
__global__ __launch_bounds__(128) void repack_cm_k(
    const float* __restrict__ sig, const float* __restrict__ rgb,
    uint4* __restrict__ out)
{
    __shared__ unsigned row[2][kG];
    int ix  = blockIdx.x >> 7;
    int iy0 = blockIdx.x & 127;
    int iy1 = min(iy0 + 1, 127);
    int z   = threadIdx.x;
    row[0][z] = packvox8(sig, rgb, (ix << 14) + (iy0 << 7) + z);
    row[1][z] = packvox8(sig, rgb, (ix << 14) + (iy1 << 7) + z);
    __syncthreads();
    int z1 = min(z + 1, 127);
    unsigned a = row[0][z], b = row[0][z1], c = row[1][z], d = row[1][z1];
    uint4 cell;
    cell.x = ( a        & 0xffu)        | (( b        & 0xffu) << 8)
           | ((c        & 0xffu) << 16) | (( d        & 0xffu) << 24);
    cell.y = ((a >>  8) & 0xffu)        | (((b >>  8) & 0xffu) << 8)
           | (((c >> 8) & 0xffu) << 16) | (((d >>  8) & 0xffu) << 24);
    cell.z = ((a >> 16) & 0xffu)        | (((b >> 16) & 0xffu) << 8)
           | (((c >> 16) & 0xffu) << 16)| (((d >> 16) & 0xffu) << 24);
    cell.w = ( a >> 24)                 | (( b >> 24) << 8)
           | ((c >> 24) << 16)          | (( d >> 24) << 24);
    out[(ix << 14) + (iy0 << 7) + z] = cell;
}

// ---------------- counting sort -------------------------------------------
__device__ __forceinline__ int cell9(float x, float y, float z)
{
    int cx = min(7, max(0, (int)((x - kBminX) * 4.0f)));
    int cy = min(7, max(0, (int)((y - kBminY) * 8.0f)));
    int cz = min(7, max(0, (int)((z - kBminZ) * 4.0f)));
    return (cx << 6) | (cy << 3) | cz;
}

__device__ __forceinline__ int pathKey(
    float ox, float oy, float oz, float dx, float dy, float dz,
    float near_, float far_)
{
    int ke = cell9(fmaf(near_, dx, ox), fmaf(near_, dy, oy), fmaf(near_, dz, oz));
    int kx = cell9(fmaf(far_,  dx, ox), fmaf(far_,  dy, oy), fmaf(far_,  dz, oz));
    return (ke << 9) | kx;
}

__global__ __launch_bounds__(256) void hist18_k(
    const float* __restrict__ rays_o, const float* __restrict__ rays_d,
    int* __restrict__ hist)
{
    int i = blockIdx.x * 256 + threadIdx.x;
    if (i >= kNRays) return;
    float ox = rays_o[3*i+0], oy = rays_o[3*i+1], oz = rays_o[3*i+2];
    float dx = rays_d[3*i+0], dy = rays_d[3*i+1], dz = rays_d[3*i+2];
    float near_, far_;
    slabNearFar(ox, oy, oz, dx, dy, dz, near_, far_);
    atomicAdd(&hist[pathKey(ox, oy, oz, dx, dy, dz, near_, far_)], 1);
}

__global__ __launch_bounds__(256) void scan_blk_k(
    int* __restrict__ h, int* __restrict__ bsum)
{
    __shared__ int tmp[256];
    int t = threadIdx.x;
    int i = blockIdx.x * 256 + t;
    int v = h[i];
    tmp[t] = v;
    __syncthreads();
    int x = v;
    for (int off = 1; off < 256; off <<= 1) {
        int y = (t >= off) ? tmp[t - off] : 0;
        __syncthreads();
        x += y;
        tmp[t] = x;
        __syncthreads();
    }
    h[i] = x - v;
    if (t == 255) bsum[blockIdx.x] = x;
}

__global__ __launch_bounds__(256) void scan_top_k(int* __restrict__ bsum)
{
    __shared__ int tmp[256];
    int t = threadIdx.x;
    int4 v = reinterpret_cast<int4*>(bsum)[t];
    int s = v.x + v.y + v.z + v.w;
    tmp[t] = s;
    __syncthreads();
    int x = s;
    for (int off = 1; off < 256; off <<= 1) {
        int y = (t >= off) ? tmp[t - off] : 0;
        __syncthreads();
        x += y;
        tmp[t] = x;
        __syncthreads();
    }
    int exc = x - s;
    reinterpret_cast<int4*>(bsum)[t] =
        make_int4(exc, exc + v.x, exc + v.x + v.y, exc + v.x + v.y + v.z);
}

// scatter: perm + pre-gathered ray data in sorted order
__global__ __launch_bounds__(256) void scatter18_k(
    const float* __restrict__ rays_o, const float* __restrict__ rays_d,
    int* __restrict__ h, const int* __restrict__ bsum, int* __restrict__ perm,
    float4* __restrict__ so4, float4* __restrict__ sd4)
{
    int i = blockIdx.x * 256 + threadIdx.x;
    if (i >= kNRays) return;
    float ox = rays_o[3*i+0], oy = rays_o[3*i+1], oz = rays_o[3*i+2];
    float dx = rays_d[3*i+0], dy = rays_d[3*i+1], dz = rays_d[3*i+2];
    float near_, far_;
    slabNearFar(ox, oy, oz, dx, dy, dz, near_, far_);
    int key = pathKey(ox, oy, oz, dx, dy, dz, near_, far_);
    float dt = (far_ - near_) * (1.0f / (float)kSteps);
    int pos = bsum[key >> 8] + atomicAdd(&h[key], 1);
    perm[pos] = i;
    so4[pos] = make_float4(ox, oy, oz, near_);
    sd4[pos] = make_float4(dx, dy, dz, dt);
}

// ---------------- fused render + merge ------------------------------------
// 1024 blocks x 512 threads; block = 256 rays x {seg0, seg1}.
__global__ __launch_bounds__(512, 8) void render_f_k(
    const float4* __restrict__ so4, const float4* __restrict__ sd4,
    const uint4* __restrict__ grid, const int* __restrict__ perm,
    const float* __restrict__ bg, float* __restrict__ out)
{
    __shared__ float4 part[256];

    int bid = blockIdx.x;                      // 1024 blocks
    int swz = (bid & 7) * 128 + (bid >> 3);    // bijective XCD chunk swizzle
    int t    = (int)threadIdx.x;
    int rloc = t & 255;
    int seg  = t >> 8;
    int sj   = swz * 256 + rloc;               // sorted ray index

    float4 o4 = so4[sj], d4 = sd4[sj];
    float ox = o4.x, oy = o4.y, oz = o4.z, near_ = o4.w;
    float dx = d4.x, dy = d4.y, dz = d4.z, dt = d4.w;
    float dtq = dt * kInvScale;

    const int nsteps = kSteps / 2;

    float t0  = fmaf(0.5f, dt, near_);
    float u0x = (fmaf(t0, dx, ox) - kBminX) * kSx;
    float u0y = (fmaf(t0, dy, oy) - kBminY) * kSy;
    float u0z = (fmaf(t0, dz, oz) - kBminZ) * kSz;
    float dux = dx * dt * kSx, duy = dy * dt * kSy, duz = dz * dt * kSz;
    float sb = (float)(seg * nsteps);
    u0x = fmaf(sb, dux, u0x); u0y = fmaf(sb, duy, u0y); u0z = fmaf(sb, duz, u0z);

    int c;
    float f0x, f0y, f0z, f1x, f1y, f1z, f2x, f2y, f2z;
    cellOf(u0x, u0y, u0z, dux, duy, duz, 0.0f, c, f0x, f0y, f0z);
    uint4 q0 = grid[c], q1 = grid[c + (1 << 14)];
    cellOf(u0x, u0y, u0z, dux, duy, duz, 1.0f, c, f1x, f1y, f1z);
    uint4 m0 = grid[c], m1 = grid[c + (1 << 14)];

    float T = 1.0f, wsum = 0.0f, ar = 0.0f, ag = 0.0f, ab = 0.0f;

    for (int s = 0; s < nsteps; ++s) {
        float sn = (float)min(s + 2, nsteps - 1);
        cellOf(u0x, u0y, u0z, dux, duy, duz, sn, c, f2x, f2y, f2z);
        uint4 n0 = grid[c], n1 = grid[c + (1 << 14)];

        float wz0 = 1.0f - f0z, wy0 = 1.0f - f0y;
        float sA, sB, rA, rB, gA, gB, bA, bB;
#if USE_UDOT4
        int w00 = __float2int_rn(wy0 * wz0 * 255.0f);
        int w01 = __float2int_rn(wy0 * f0z * 255.0f);
        int w10 = __float2int_rn(f0y * wz0 * 255.0f);
        int w11 = 255 - w00 - w01 - w10;
        w11 = max(w11, 0);
        unsigned wp = (unsigned)(w00 | (w01 << 8) | (w10 << 16) | (w11 << 24));
        sA = (float)__builtin_amdgcn_udot4(q0.x, wp, 0u, false);
        rA = (float)__builtin_amdgcn_udot4(q0.y, wp, 0u, false);
        gA = (float)__builtin_amdgcn_udot4(q0.z, wp, 0u, false);
        bA = (float)__builtin_amdgcn_udot4(q0.w, wp, 0u, false);
        sB = (float)__builtin_amdgcn_udot4(q1.x, wp, 0u, false);
        rB = (float)__builtin_amdgcn_udot4(q1.y, wp, 0u, false);
        gB = (float)__builtin_amdgcn_udot4(q1.z, wp, 0u, false);
        bB = (float)__builtin_amdgcn_udot4(q1.w, wp, 0u, false);
#else
        float w00 = wy0 * wz0, w01 = wy0 * f0z, w10 = f0y * wz0, w11 = f0y * f0z;
        #define CB0(u) ((float)((u) & 0xffu))
        #define CB1(u) ((float)(((u) >> 8) & 0xffu))
        #define CB2(u) ((float)(((u) >> 16) & 0xffu))
        #define CB3(u) ((float)((u) >> 24))
        sA = w00*CB0(q0.x) + w01*CB1(q0.x) + w10*CB2(q0.x) + w11*CB3(q0.x);
        rA = w00*CB0(q0.y) + w01*CB1(q0.y) + w10*CB2(q0.y) + w11*CB3(q0.y);
        gA = w00*CB0(q0.z) + w01*CB1(q0.z) + w10*CB2(q0.z) + w11*CB3(q0.z);
        bA = w00*CB0(q0.w) + w01*CB1(q0.w) + w10*CB2(q0.w) + w11*CB3(q0.w);
        sB = w00*CB0(q1.x) + w01*CB1(q1.x) + w10*CB2(q1.x) + w11*CB3(q1.x);
        rB = w00*CB0(q1.y) + w01*CB1(q1.y) + w10*CB2(q1.y) + w11*CB3(q1.y);
        gB = w00*CB0(q1.z) + w01*CB1(q1.z) + w10*CB2(q1.z) + w11*CB3(q1.z);
        bB = w00*CB0(q1.w) + w01*CB1(q1.w) + w10*CB2(q1.w) + w11*CB3(q1.w);
#endif
        float sv = fmaf(f0x, sB - sA, sA);      // raw kScale units
        float rv = fmaf(f0x, rB - rA, rA);
        float gv = fmaf(f0x, gB - gA, gA);
        float bv = fmaf(f0x, bB - bA, bA);

        float sigr  = (sv > kSigThr) ? sv : 0.0f;          // sigma > 0.01
        float alpha = 1.0f - __expf(-sigr * dtq);
        alpha = (T > kTTh) ? alpha : 0.0f;                  // reference gating
        float w = alpha * T;
        T *= (1.0f - alpha);
        wsum += w;
        ar = fmaf(w, rv, ar);
        ag = fmaf(w, gv, ag);
        ab = fmaf(w, bv, ab);

        q0 = m0; q1 = m1; m0 = n0; m1 = n1;
        f0x = f1x; f0y = f1y; f0z = f1z;
        f1x = f2x; f1y = f2y; f1z = f2z;
    }

    if (seg == 1) part[rloc] = make_float4(ar, ag, ab, wsum);
    __syncthreads();
    if (seg == 0) {
        float4 b = part[rloc];
        ar = fmaf(T, b.x, ar);
        ag = fmaf(T, b.y, ag);
        ab = fmaf(T, b.z, ab);
        float ws = fmaf(T, b.w, wsum);
        int ray = perm[sj];
        float omw = 1.0f - ws;
        out[3 * ray + 0] = fminf(fmaxf(fmaf(omw, bg[0], ar * kInvScale), 0.0f), 1.0f);
        out[3 * ray + 1] = fminf(fmaxf(fmaf(omw, bg[1], ag * kInvScale), 0.0f), 1.0f);
        out[3 * ray + 2] = fminf(fmaxf(fmaf(omw, bg[2], ab * kInvScale), 0.0f), 1.0f);
    }
}

// ---------------- plain fallback ------------------------------------------
__global__ __launch_bounds__(256) void render_plain_k(
    const float* __restrict__ rays_o, const float* __restrict__ rays_d,
    const float* __restrict__ sgrid, const float* __restrict__ cgrid,
    const float* __restrict__ bg, float* __restrict__ out)
{
    int i = blockIdx.x * 256 + threadIdx.x;
    if (i >= kNRays) return;
    float ox = rays_o[3*i+0], oy = rays_o[3*i+1], oz = rays_o[3*i+2];
    float dx = rays_d[3*i+0], dy = rays_d[3*i+1], dz = rays_d[3*i+2];
    float near_, far_;
    slabNearFar(ox, oy, oz, dx, dy, dz, near_, far_);
    float dt = (far_ - near_) * (1.0f / (float)kSteps);
    float t0  = fmaf(0.5f, dt, near_);
    float u0x = (fmaf(t0, dx, ox) - kBminX) * kSx;
    float u0y = (fmaf(t0, dy, oy) - kBminY) * kSy;
    float u0z = (fmaf(t0, dz, oz) - kBminZ) * kSz;
    float dux = dx * dt * kSx, duy = dy * dt * kSy, duz = dz * dt * kSz;
    float T = 1.0f, wsum = 0.0f, accr = 0.0f, accg = 0.0f, accb = 0.0f;
    for (int s = 0; s < kSteps; ++s) {
        int base; float fx, fy, fz;
        cellOf(u0x, u0y, u0z, dux, duy, duz, (float)s, base, fx, fy, fz);
        float w0x = 1.0f - fx, w0y = 1.0f - fy, w0z = 1.0f - fz;
        float wa = w0x*w0y*w0z, wb = w0x*w0y*fz, wc = w0x*fy*w0z, wd = w0x*fy*fz;
        float we = fx*w0y*w0z,  wf = fx*w0y*fz,  wg = fx*fy*w0z,  wh = fx*fy*fz;
        int i000 = base, i001 = base + 1, i010 = base + kG, i011 = base + kG + 1;
        int i100 = base + kG*kG, i101 = i100 + 1, i110 = i100 + kG, i111 = i110 + 1;
        float sv = wa*sgrid[i000] + wb*sgrid[i001] + wc*sgrid[i010] + wd*sgrid[i011]
                 + we*sgrid[i100] + wf*sgrid[i101] + wg*sgrid[i110] + wh*sgrid[i111];
        float rv = wa*cgrid[3*i000+0] + wb*cgrid[3*i001+0] + wc*cgrid[3*i010+0] + wd*cgrid[3*i011+0]
                 + we*cgrid[3*i100+0] + wf*cgrid[3*i101+0] + wg*cgrid[3*i110+0] + wh*cgrid[3*i111+0];
        float gv = wa*cgrid[3*i000+1] + wb*cgrid[3*i001+1] + wc*cgrid[3*i010+1] + wd*cgrid[3*i011+1]
                 + we*cgrid[3*i100+1] + wf*cgrid[3*i101+1] + wg*cgrid[3*i110+1] + wh*cgrid[3*i111+1];
        float bv = wa*cgrid[3*i000+2] + wb*cgrid[3*i001+2] + wc*cgrid[3*i010+2] + wd*cgrid[3*i011+2]
                 + we*cgrid[3*i100+2] + wf*cgrid[3*i101+2] + wg*cgrid[3*i110+2] + wh*cgrid[3*i111+2];
        float sig = (sv > 0.01f) ? sv : 0.0f;
        float alpha = 1.0f - __expf(-sig * dt);
        float w = alpha * T;
        T *= (1.0f - alpha);
        wsum += w;
        accr = fmaf(w, rv, accr); accg = fmaf(w, gv, accg); accb = fmaf(w, bv, accb);
        if (T <= kTTh) break;
    }
    float omw = 1.0f - wsum;
    out[3 * i + 0] = fminf(fmaxf(fmaf(omw, bg[0], accr), 0.0f), 1.0f);
    out[3 * i + 1] = fminf(fmaxf(fmaf(omw, bg[1], accg), 0.0f), 1.0f);
    out[3 * i + 2] = fminf(fmaxf(fmaf(omw, bg[2], accb), 0.0f), 1.0f);
}

extern "C" void kernel_launch(void* const* d_in, const int* in_sizes, int n_in,
                              void* d_out, int out_size, void* d_ws, size_t ws_size,
                              hipStream_t stream)
{
    const float* rays_o = (const float*)d_in[0];
    const float* rays_d = (const float*)d_in[1];
    const float* sgrid  = (const float*)d_in[2];
    const float* cgrid  = (const float*)d_in[3];
    const float* bg     = (const float*)d_in[4];
    float* out = (float*)d_out;

    const int RB_BLK = kNRays / 256;   // 1024

    // grid 32MiB | hist 1MiB | bsum 4KiB | perm 1MiB | so4 4MiB | sd4 4MiB
    size_t a_grid = 0;
    size_t a_hist = a_grid + (size_t)kG3 * sizeof(uint4);
    size_t a_bsum = a_hist + (size_t)kSB * sizeof(int);
    size_t a_perm = a_bsum + (size_t)1024 * sizeof(int);
    size_t a_so4  = a_perm + (size_t)kNRays * sizeof(int);
    size_t a_sd4  = a_so4  + (size_t)kNRays * sizeof(float4);
    size_t needA  = a_sd4  + (size_t)kNRays * sizeof(float4);

    if (ws_size >= needA) {
        char* ws = (char*)d_ws;
        uint4*  grid = (uint4*)(ws + a_grid);
        int*    hist = (int*)(ws + a_hist);
        int*    bsum = (int*)(ws + a_bsum);
        int*    perm = (int*)(ws + a_perm);
        float4* so4  = (float4*)(ws + a_so4);
        float4* sd4  = (float4*)(ws + a_sd4);

        repack_cm_k<<<kG * kG, 128, 0, stream>>>(sgrid, cgrid, grid);
        hipMemsetAsync(hist, 0, (size_t)kSB * sizeof(int), stream);
        hist18_k<<<RB_BLK, 256, 0, stream>>>(rays_o, rays_d, hist);
        scan_blk_k<<<kSB / 256, 256, 0, stream>>>(hist, bsum);
        scan_top_k<<<1, 256, 0, stream>>>(bsum);
        scatter18_k<<<RB_BLK, 256, 0, stream>>>(rays_o, rays_d, hist, bsum,
                                                perm, so4, sd4);
        render_f_k<<<kNRays / 256, 512, 0, stream>>>(so4, sd4, grid, perm, bg, out);
    } else {
        render_plain_k<<<RB_BLK, 256, 0, stream>>>(
            rays_o, rays_d, sgrid, cgrid, bg, out);
    }
}

// Round 9
// 257.379 us; speedup vs baseline: 1.9125x; 1.2995x over previous
//
#include <hip/hip_runtime.h>

// NeRF ray-marching renderer, MI355X — round 9.
//  - 22-bit path key: entry FACE coords at 4-voxel res (32x32, 10b) +
//    exit 3D at 8-voxel res (16x16x16, 12b, z fastest). Waves become
//    ~4-8 voxel tubes -> intra-wave gather coalescing (round-8 was ~60
//    lines/gather; predict ~20).
//  - 3-level hierarchical scan over 2^22 buckets (all coalesced).
//  - Fat kernel: repack || hist in one dispatch.
//  - Render identical to round 8 (udot4 corner-major cells, fused merge,
//    XCD swizzle, 2-deep prefetch) to isolate the sort-quality delta.

constexpr int   kG     = 128;
constexpr int   kG3    = kG * kG * kG;
constexpr int   kSteps = 128;
constexpr int   kNRays = 262144;          // 2^18
constexpr int   kKB    = 1 << 22;         // sort buckets (22-bit key)
constexpr float kBminX = -1.0f, kBminY = -0.5f, kBminZ = -1.0f;
constexpr float kBmaxX =  1.0f, kBmaxY =  0.5f, kBmaxZ =  1.0f;
constexpr float kSx = 63.5f, kSy = 127.0f, kSz = 63.5f;   // (G-1)/extent
constexpr float kMinNear = 0.05f;
constexpr float kTTh     = 1e-4f;

#if __has_builtin(__builtin_amdgcn_udot4)
#define USE_UDOT4 1
constexpr float kScale  = 65025.0f;       // 255 (value) * 255 (weight)
#else
#define USE_UDOT4 0
constexpr float kScale  = 255.0f;
#endif
constexpr float kInvScale = 1.0f / kScale;
constexpr float kSigThr   = 0.01f * kScale;

// ---------------- shared helpers ------------------------------------------
__device__ __forceinline__ void slabNearFar(
    float ox, float oy, float oz, float dx, float dy, float dz,
    float& near_, float& far_)
{
    float sdx = (fabsf(dx) < 1e-9f) ? 1e-9f : dx;
    float sdy = (fabsf(dy) < 1e-9f) ? 1e-9f : dy;
    float sdz = (fabsf(dz) < 1e-9f) ? 1e-9f : dz;
    float t1x = (kBminX - ox) / sdx, t2x = (kBmaxX - ox) / sdx;
    float t1y = (kBminY - oy) / sdy, t2y = (kBmaxY - oy) / sdy;
    float t1z = (kBminZ - oz) / sdz, t2z = (kBmaxZ - oz) / sdz;
    near_ = fmaxf(fmaxf(fminf(t1x, t2x), fminf(t1y, t2y)), fminf(t1z, t2z));
    far_  = fminf(fminf(fmaxf(t1x, t2x), fmaxf(t1y, t2y)), fmaxf(t1z, t2z));
    near_ = fmaxf(near_, kMinNear);
    far_  = fmaxf(far_, near_ + 1e-6f);
}

// grid coords linear in step index: u(s) = u0 + s*du (per axis)
__device__ __forceinline__ void cellOf(
    float u0x, float u0y, float u0z, float dux, float duy, float duz,
    float sf, int& cell, float& fx, float& fy, float& fz)
{
    float ux = fminf(fmaxf(fmaf(sf, dux, u0x), 0.0f), 127.0f);
    float uy = fminf(fmaxf(fmaf(sf, duy, u0y), 0.0f), 127.0f);
    float uz = fminf(fmaxf(fmaf(sf, duz, u0z), 0.0f), 127.0f);
    float cx = fminf(floorf(ux), 126.0f);
    float cy = fminf(floorf(uy), 126.0f);
    float cz = fminf(floorf(uz), 126.0f);
    fx = ux - cx; fy = uy - cy; fz = uz - cz;
    cell = ((int)cx << 14) + ((int)cy << 7) + (int)cz;
}

// 22-bit path key: [entry_y5 entry_x5 | exit_x4 exit_y4 exit_z4]
__device__ __forceinline__ int pathKey22(
    float ox, float oy, float oz, float dx, float dy, float dz,
    float near_, float far_)
{
    float exw = fmaf(near_, dx, ox), eyw = fmaf(near_, dy, oy);
    int ex = min(31, max(0, (int)((exw - kBminX) * 16.0f)));   // 4.06-voxel
    int ey = min(31, max(0, (int)((eyw - kBminY) * 32.0f)));   // 4-voxel
    float xx = fmaf(far_, dx, ox), xy = fmaf(far_, dy, oy), xz = fmaf(far_, dz, oz);
    int qx = min(15, max(0, (int)((xx - kBminX) * 8.0f)));     // 8-voxel
    int qy = min(15, max(0, (int)((xy - kBminY) * 16.0f)));    // 8-voxel
    int qz = min(15, max(0, (int)((xz - kBminZ) * 8.0f)));     // 8-voxel, fastest
    return (((ey << 5) | ex) << 12) | (qx << 8) | (qy << 4) | qz;
}

// ---------------- fat kernel: repack || hist ------------------------------
__device__ __forceinline__ unsigned packvox8(
    const float* __restrict__ sig, const float* __restrict__ rgb, int idx)
{
    unsigned s = (unsigned)__float2int_rn(fminf(fmaxf(sig[idx], 0.f), 1.f) * 255.f);
    unsigned r = (unsigned)__float2int_rn(fminf(fmaxf(rgb[3*idx+0], 0.f), 1.f) * 255.f);
    unsigned g = (unsigned)__float2int_rn(fminf(fmaxf(rgb[3*idx+1], 0.f), 1.f) * 255.f);
    unsigned b = (unsigned)__float2int_rn(fminf(fmaxf(rgb[3*idx+2], 0.f), 1.f) * 255.f);
    return s | (r << 8) | (g << 16) | (b << 24);
}

// blocks [0, 16384): corner-major u8 repack. blocks [16384, 18432): key hist.
__global__ __launch_bounds__(128) void fat_k(
    const float* __restrict__ sig, const float* __restrict__ rgb,
    uint4* __restrict__ gout,
    const float* __restrict__ rays_o, const float* __restrict__ rays_d,
    int* __restrict__ hist)
{
    int bid = blockIdx.x;
    if (bid < kG * kG) {
        __shared__ unsigned row[2][kG];
        int ix  = bid >> 7;
        int iy0 = bid & 127;
        int iy1 = min(iy0 + 1, 127);
        int z   = threadIdx.x;
        row[0][z] = packvox8(sig, rgb, (ix << 14) + (iy0 << 7) + z);
        row[1][z] = packvox8(sig, rgb, (ix << 14) + (iy1 << 7) + z);
        __syncthreads();
        int z1 = min(z + 1, 127);
        unsigned a = row[0][z], b = row[0][z1], c = row[1][z], d = row[1][z1];
        uint4 cell;
        cell.x = ( a        & 0xffu)        | (( b        & 0xffu) << 8)
               | ((c        & 0xffu) << 16) | (( d        & 0xffu) << 24);
        cell.y = ((a >>  8) & 0xffu)        | (((b >>  8) & 0xffu) << 8)
               | (((c >> 8) & 0xffu) << 16) | (((d >>  8) & 0xffu) << 24);
        cell.z = ((a >> 16) & 0xffu)        | (((b >> 16) & 0xffu) << 8)
               | (((c >> 16) & 0xffu) << 16)| (((d >> 16) & 0xffu) << 24);
        cell.w = ( a >> 24)                 | (( b >> 24) << 8)
               | ((c >> 24) << 16)          | (( d >> 24) << 24);
        gout[(ix << 14) + (iy0 << 7) + z] = cell;
    } else {
        int i = (bid - kG * kG) * 128 + (int)threadIdx.x;
        if (i >= kNRays) return;
        float ox = rays_o[3*i+0], oy = rays_o[3*i+1], oz = rays_o[3*i+2];
        float dx = rays_d[3*i+0], dy = rays_d[3*i+1], dz = rays_d[3*i+2];
        float near_, far_;
        slabNearFar(ox, oy, oz, dx, dy, dz, near_, far_);
        atomicAdd(&hist[pathKey22(ox, oy, oz, dx, dy, dz, near_, far_)], 1);
    }
}

// ---------------- hierarchical scan ---------------------------------------
// per-256-block exclusive scan; h[i] <- local exclusive, bsum[b] <- block total
__global__ __launch_bounds__(256) void scan_blk_k(
    int* __restrict__ h, int* __restrict__ bsum)
{
    __shared__ int tmp[256];
    int t = threadIdx.x;
    int i = blockIdx.x * 256 + t;
    int v = h[i];
    tmp[t] = v;
    __syncthreads();
    int x = v;
    for (int off = 1; off < 256; off <<= 1) {
        int y = (t >= off) ? tmp[t - off] : 0;
        __syncthreads();
        x += y;
        tmp[t] = x;
        __syncthreads();
    }
    h[i] = x - v;
    if (t == 255) bsum[blockIdx.x] = x;
}

// exclusive scan of 64 ints in one wave
__global__ __launch_bounds__(64) void scan_top64_k(int* __restrict__ b)
{
    int t = threadIdx.x;
    int v = b[t];
    int x = v;
    for (int off = 1; off < 64; off <<= 1) {
        int y = __shfl_up(x, off);
        if (t >= off) x += y;
    }
    b[t] = x - v;
}

// scatter: pos = bsum2[key>>16] + bsum[key>>8] + atomicAdd(h[key])
__global__ __launch_bounds__(256) void scatter22_k(
    const float* __restrict__ rays_o, const float* __restrict__ rays_d,
    int* __restrict__ h, const int* __restrict__ bsum,
    const int* __restrict__ bsum2, int* __restrict__ perm,
    float4* __restrict__ so4, float4* __restrict__ sd4)
{
    int i = blockIdx.x * 256 + threadIdx.x;
    if (i >= kNRays) return;
    float ox = rays_o[3*i+0], oy = rays_o[3*i+1], oz = rays_o[3*i+2];
    float dx = rays_d[3*i+0], dy = rays_d[3*i+1], dz = rays_d[3*i+2];
    float near_, far_;
    slabNearFar(ox, oy, oz, dx, dy, dz, near_, far_);
    int key = pathKey22(ox, oy, oz, dx, dy, dz, near_, far_);
    float dt = (far_ - near_) * (1.0f / (float)kSteps);
    int pos = bsum2[key >> 16] + bsum[key >> 8] + atomicAdd(&h[key], 1);
    perm[pos] = i;
    so4[pos] = make_float4(ox, oy, oz, near_);
    sd4[pos] = make_float4(dx, dy, dz, dt);
}

// ---------------- fused render + merge ------------------------------------
// 1024 blocks x 512 threads; block = 256 rays x {seg0, seg1}.
__global__ __launch_bounds__(512, 8) void render_f_k(
    const float4* __restrict__ so4, const float4* __restrict__ sd4,
    const uint4* __restrict__ grid, const int* __restrict__ perm,
    const float* __restrict__ bg, float* __restrict__ out)
{
    __shared__ float4 part[256];

    int bid = blockIdx.x;                      // 1024 blocks
    int swz = (bid & 7) * 128 + (bid >> 3);    // bijective XCD chunk swizzle
    int t    = (int)threadIdx.x;
    int rloc = t & 255;
    int seg  = t >> 8;
    int sj   = swz * 256 + rloc;               // sorted ray index

    float4 o4 = so4[sj], d4 = sd4[sj];
    float ox = o4.x, oy = o4.y, oz = o4.z, near_ = o4.w;
    float dx = d4.x, dy = d4.y, dz = d4.z, dt = d4.w;
    float dtq = dt * kInvScale;

    const int nsteps = kSteps / 2;

    float t0  = fmaf(0.5f, dt, near_);
    float u0x = (fmaf(t0, dx, ox) - kBminX) * kSx;
    float u0y = (fmaf(t0, dy, oy) - kBminY) * kSy;
    float u0z = (fmaf(t0, dz, oz) - kBminZ) * kSz;
    float dux = dx * dt * kSx, duy = dy * dt * kSy, duz = dz * dt * kSz;
    float sb = (float)(seg * nsteps);
    u0x = fmaf(sb, dux, u0x); u0y = fmaf(sb, duy, u0y); u0z = fmaf(sb, duz, u0z);

    int c;
    float f0x, f0y, f0z, f1x, f1y, f1z, f2x, f2y, f2z;
    cellOf(u0x, u0y, u0z, dux, duy, duz, 0.0f, c, f0x, f0y, f0z);
    uint4 q0 = grid[c], q1 = grid[c + (1 << 14)];
    cellOf(u0x, u0y, u0z, dux, duy, duz, 1.0f, c, f1x, f1y, f1z);
    uint4 m0 = grid[c], m1 = grid[c + (1 << 14)];

    float T = 1.0f, wsum = 0.0f, ar = 0.0f, ag = 0.0f, ab = 0.0f;

    for (int s = 0; s < nsteps; ++s) {
        float sn = (float)min(s + 2, nsteps - 1);
        cellOf(u0x, u0y, u0z, dux, duy, duz, sn, c, f2x, f2y, f2z);
        uint4 n0 = grid[c], n1 = grid[c + (1 << 14)];

        float wz0 = 1.0f - f0z, wy0 = 1.0f - f0y;
        float sA, sB, rA, rB, gA, gB, bA, bB;
#if USE_UDOT4
        int w00 = __float2int_rn(wy0 * wz0 * 255.0f);
        int w01 = __float2int_rn(wy0 * f0z * 255.0f);
        int w10 = __float2int_rn(f0y * wz0 * 255.0f);
        int w11 = 255 - w00 - w01 - w10;
        w11 = max(w11, 0);
        unsigned wp = (unsigned)(w00 | (w01 << 8) | (w10 << 16) | (w11 << 24));
        sA = (float)__builtin_amdgcn_udot4(q0.x, wp, 0u, false);
        rA = (float)__builtin_amdgcn_udot4(q0.y, wp, 0u, false);
        gA = (float)__builtin_amdgcn_udot4(q0.z, wp, 0u, false);
        bA = (float)__builtin_amdgcn_udot4(q0.w, wp, 0u, false);
        sB = (float)__builtin_amdgcn_udot4(q1.x, wp, 0u, false);
        rB = (float)__builtin_amdgcn_udot4(q1.y, wp, 0u, false);
        gB = (float)__builtin_amdgcn_udot4(q1.z, wp, 0u, false);
        bB = (float)__builtin_amdgcn_udot4(q1.w, wp, 0u, false);
#else
        float w00 = wy0 * wz0, w01 = wy0 * f0z, w10 = f0y * wz0, w11 = f0y * f0z;
        #define CB0(u) ((float)((u) & 0xffu))
        #define CB1(u) ((float)(((u) >> 8) & 0xffu))
        #define CB2(u) ((float)(((u) >> 16) & 0xffu))
        #define CB3(u) ((float)((u) >> 24))
        sA = w00*CB0(q0.x) + w01*CB1(q0.x) + w10*CB2(q0.x) + w11*CB3(q0.x);
        rA = w00*CB0(q0.y) + w01*CB1(q0.y) + w10*CB2(q0.y) + w11*CB3(q0.y);
        gA = w00*CB0(q0.z) + w01*CB1(q0.z) + w10*CB2(q0.z) + w11*CB3(q0.z);
        bA = w00*CB0(q0.w) + w01*CB1(q0.w) + w10*CB2(q0.w) + w11*CB3(q0.w);
        sB = w00*CB0(q1.x) + w01*CB1(q1.x) + w10*CB2(q1.x) + w11*CB3(q1.x);
        rB = w00*CB0(q1.y) + w01*CB1(q1.y) + w10*CB2(q1.y) + w11*CB3(q1.y);
        gB = w00*CB0(q1.z) + w01*CB1(q1.z) + w10*CB2(q1.z) + w11*CB3(q1.z);
        bB = w00*CB0(q1.w) + w01*CB1(q1.w) + w10*CB2(q1.w) + w11*CB3(q1.w);
#endif
        float sv = fmaf(f0x, sB - sA, sA);      // raw kScale units
        float rv = fmaf(f0x, rB - rA, rA);
        float gv = fmaf(f0x, gB - gA, gA);
        float bv = fmaf(f0x, bB - bA, bA);

        float sigr  = (sv > kSigThr) ? sv : 0.0f;          // sigma > 0.01
        float alpha = 1.0f - __expf(-sigr * dtq);
        alpha = (T > kTTh) ? alpha : 0.0f;                  // reference gating
        float w = alpha * T;
        T *= (1.0f - alpha);
        wsum += w;
        ar = fmaf(w, rv, ar);
        ag = fmaf(w, gv, ag);
        ab = fmaf(w, bv, ab);

        q0 = m0; q1 = m1; m0 = n0; m1 = n1;
        f0x = f1x; f0y = f1y; f0z = f1z;
        f1x = f2x; f1y = f2y; f1z = f2z;
    }

    if (seg == 1) part[rloc] = make_float4(ar, ag, ab, wsum);
    __syncthreads();
    if (seg == 0) {
        float4 b = part[rloc];
        ar = fmaf(T, b.x, ar);
        ag = fmaf(T, b.y, ag);
        ab = fmaf(T, b.z, ab);
        float ws = fmaf(T, b.w, wsum);
        int ray = perm[sj];
        float omw = 1.0f - ws;
        out[3 * ray + 0] = fminf(fmaxf(fmaf(omw, bg[0], ar * kInvScale), 0.0f), 1.0f);
        out[3 * ray + 1] = fminf(fmaxf(fmaf(omw, bg[1], ag * kInvScale), 0.0f), 1.0f);
        out[3 * ray + 2] = fminf(fmaxf(fmaf(omw, bg[2], ab * kInvScale), 0.0f), 1.0f);
    }
}

// ---------------- plain fallback ------------------------------------------
__global__ __launch_bounds__(256) void render_plain_k(
    const float* __restrict__ rays_o, const float* __restrict__ rays_d,
    const float* __restrict__ sgrid, const float* __restrict__ cgrid,
    const float* __restrict__ bg, float* __restrict__ out)
{
    int i = blockIdx.x * 256 + threadIdx.x;
    if (i >= kNRays) return;
    float ox = rays_o[3*i+0], oy = rays_o[3*i+1], oz = rays_o[3*i+2];
    float dx = rays_d[3*i+0], dy = rays_d[3*i+1], dz = rays_d[3*i+2];
    float near_, far_;
    slabNearFar(ox, oy, oz, dx, dy, dz, near_, far_);
    float dt = (far_ - near_) * (1.0f / (float)kSteps);
    float t0  = fmaf(0.5f, dt, near_);
    float u0x = (fmaf(t0, dx, ox) - kBminX) * kSx;
    float u0y = (fmaf(t0, dy, oy) - kBminY) * kSy;
    float u0z = (fmaf(t0, dz, oz) - kBminZ) * kSz;
    float dux = dx * dt * kSx, duy = dy * dt * kSy, duz = dz * dt * kSz;
    float T = 1.0f, wsum = 0.0f, accr = 0.0f, accg = 0.0f, accb = 0.0f;
    for (int s = 0; s < kSteps; ++s) {
        int base; float fx, fy, fz;
        cellOf(u0x, u0y, u0z, dux, duy, duz, (float)s, base, fx, fy, fz);
        float w0x = 1.0f - fx, w0y = 1.0f - fy, w0z = 1.0f - fz;
        float wa = w0x*w0y*w0z, wb = w0x*w0y*fz, wc = w0x*fy*w0z, wd = w0x*fy*fz;
        float we = fx*w0y*w0z,  wf = fx*w0y*fz,  wg = fx*fy*w0z,  wh = fx*fy*fz;
        int i000 = base, i001 = base + 1, i010 = base + kG, i011 = base + kG + 1;
        int i100 = base + kG*kG, i101 = i100 + 1, i110 = i100 + kG, i111 = i110 + 1;
        float sv = wa*sgrid[i000] + wb*sgrid[i001] + wc*sgrid[i010] + wd*sgrid[i011]
                 + we*sgrid[i100] + wf*sgrid[i101] + wg*sgrid[i110] + wh*sgrid[i111];
        float rv = wa*cgrid[3*i000+0] + wb*cgrid[3*i001+0] + wc*cgrid[3*i010+0] + wd*cgrid[3*i011+0]
                 + we*cgrid[3*i100+0] + wf*cgrid[3*i101+0] + wg*cgrid[3*i110+0] + wh*cgrid[3*i111+0];
        float gv = wa*cgrid[3*i000+1] + wb*cgrid[3*i001+1] + wc*cgrid[3*i010+1] + wd*cgrid[3*i011+1]
                 + we*cgrid[3*i100+1] + wf*cgrid[3*i101+1] + wg*cgrid[3*i110+1] + wh*cgrid[3*i111+1];
        float bv = wa*cgrid[3*i000+2] + wb*cgrid[3*i001+2] + wc*cgrid[3*i010+2] + wd*cgrid[3*i011+2]
                 + we*cgrid[3*i100+2] + wf*cgrid[3*i101+2] + wg*cgrid[3*i110+2] + wh*cgrid[3*i111+2];
        float sig = (sv > 0.01f) ? sv : 0.0f;
        float alpha = 1.0f - __expf(-sig * dt);
        float w = alpha * T;
        T *= (1.0f - alpha);
        wsum += w;
        accr = fmaf(w, rv, accr); accg = fmaf(w, gv, accg); accb = fmaf(w, bv, accb);
        if (T <= kTTh) break;
    }
    float omw = 1.0f - wsum;
    out[3 * i + 0] = fminf(fmaxf(fmaf(omw, bg[0], accr), 0.0f), 1.0f);
    out[3 * i + 1] = fminf(fmaxf(fmaf(omw, bg[1], accg), 0.0f), 1.0f);
    out[3 * i + 2] = fminf(fmaxf(fmaf(omw, bg[2], accb), 0.0f), 1.0f);
}

extern "C" void kernel_launch(void* const* d_in, const int* in_sizes, int n_in,
                              void* d_out, int out_size, void* d_ws, size_t ws_size,
                              hipStream_t stream)
{
    const float* rays_o = (const float*)d_in[0];
    const float* rays_d = (const float*)d_in[1];
    const float* sgrid  = (const float*)d_in[2];
    const float* cgrid  = (const float*)d_in[3];
    const float* bg     = (const float*)d_in[4];
    float* out = (float*)d_out;

    const int RB_BLK = kNRays / 256;   // 1024

    // grid 32MiB | hist 16MiB | bsum 64KiB | bsum2 256B | perm 1MiB
    // | so4 4MiB | sd4 4MiB  ~= 57.1 MiB
    size_t a_grid  = 0;
    size_t a_hist  = a_grid  + (size_t)kG3 * sizeof(uint4);
    size_t a_bsum  = a_hist  + (size_t)kKB * sizeof(int);
    size_t a_bsum2 = a_bsum  + (size_t)(kKB / 256) * sizeof(int);
    size_t a_perm  = a_bsum2 + (size_t)64 * sizeof(int);
    size_t a_so4   = a_perm  + (size_t)kNRays * sizeof(int);
    size_t a_sd4   = a_so4   + (size_t)kNRays * sizeof(float4);
    size_t needA   = a_sd4   + (size_t)kNRays * sizeof(float4);

    if (ws_size >= needA) {
        char* ws = (char*)d_ws;
        uint4*  grid  = (uint4*)(ws + a_grid);
        int*    hist  = (int*)(ws + a_hist);
        int*    bsum  = (int*)(ws + a_bsum);
        int*    bsum2 = (int*)(ws + a_bsum2);
        int*    perm  = (int*)(ws + a_perm);
        float4* so4   = (float4*)(ws + a_so4);
        float4* sd4   = (float4*)(ws + a_sd4);

        hipMemsetAsync(hist, 0, (size_t)kKB * sizeof(int), stream);
        fat_k<<<kG * kG + kNRays / 128, 128, 0, stream>>>(
            sgrid, cgrid, grid, rays_o, rays_d, hist);
        scan_blk_k<<<kKB / 256, 256, 0, stream>>>(hist, bsum);
        scan_blk_k<<<kKB / 65536, 256, 0, stream>>>(bsum, bsum2);
        scan_top64_k<<<1, 64, 0, stream>>>(bsum2);
        scatter22_k<<<RB_BLK, 256, 0, stream>>>(rays_o, rays_d, hist, bsum,
                                                bsum2, perm, so4, sd4);
        render_f_k<<<kNRays / 256, 512, 0, stream>>>(so4, sd4, grid, perm, bg, out);
    } else {
        render_plain_k<<<RB_BLK, 256, 0, stream>>>(
            rays_o, rays_d, sgrid, cgrid, bg, out);
    }
}

// Round 10
// 220.782 us; speedup vs baseline: 2.2296x; 1.1658x over previous
//
#include <hip/hip_runtime.h>

// NeRF ray-marching renderer, MI355X — round 10.
//  - X-FASTEST cell layout: cellIdx = (iy<<14)+(iz<<7)+ix. The per-step
//    x0/x1 cell pair is now 16B apart (often ONE 64B line, was 64KB apart
//    = always 2 lines), and a line spans 4 x-neighbors = the tube
//    cross-section axis -> cross-lane line sharing. Predicts ~2x fewer
//    TA line-requests in the render loop.
//  - Everything else identical to round 9 (22-bit path sort, fat
//    repack||hist kernel, udot4 corner-major cells, fused merge, XCD
//    swizzle, 2-deep prefetch) to isolate the layout delta.

constexpr int   kG     = 128;
constexpr int   kG3    = kG * kG * kG;
constexpr int   kSteps = 128;
constexpr int   kNRays = 262144;          // 2^18
constexpr int   kKB    = 1 << 22;         // sort buckets (22-bit key)
constexpr float kBminX = -1.0f, kBminY = -0.5f, kBminZ = -1.0f;
constexpr float kBmaxX =  1.0f, kBmaxY =  0.5f, kBmaxZ =  1.0f;
constexpr float kSx = 63.5f, kSy = 127.0f, kSz = 63.5f;   // (G-1)/extent
constexpr float kMinNear = 0.05f;
constexpr float kTTh     = 1e-4f;

#if __has_builtin(__builtin_amdgcn_udot4)
#define USE_UDOT4 1
constexpr float kScale  = 65025.0f;       // 255 (value) * 255 (weight)
#else
#define USE_UDOT4 0
constexpr float kScale  = 255.0f;
#endif
constexpr float kInvScale = 1.0f / kScale;
constexpr float kSigThr   = 0.01f * kScale;

// ---------------- shared helpers ------------------------------------------
__device__ __forceinline__ void slabNearFar(
    float ox, float oy, float oz, float dx, float dy, float dz,
    float& near_, float& far_)
{
    float sdx = (fabsf(dx) < 1e-9f) ? 1e-9f : dx;
    float sdy = (fabsf(dy) < 1e-9f) ? 1e-9f : dy;
    float sdz = (fabsf(dz) < 1e-9f) ? 1e-9f : dz;
    float t1x = (kBminX - ox) / sdx, t2x = (kBmaxX - ox) / sdx;
    float t1y = (kBminY - oy) / sdy, t2y = (kBmaxY - oy) / sdy;
    float t1z = (kBminZ - oz) / sdz, t2z = (kBmaxZ - oz) / sdz;
    near_ = fmaxf(fmaxf(fminf(t1x, t2x), fminf(t1y, t2y)), fminf(t1z, t2z));
    far_  = fminf(fminf(fmaxf(t1x, t2x), fmaxf(t1y, t2y)), fmaxf(t1z, t2z));
    near_ = fmaxf(near_, kMinNear);
    far_  = fmaxf(far_, near_ + 1e-6f);
}

// grid coords linear in step index: u(s) = u0 + s*du (per axis).
// X-FASTEST layout: cell = (cy<<14) + (cz<<7) + cx; x-neighbor = cell+1.
__device__ __forceinline__ void cellOf(
    float u0x, float u0y, float u0z, float dux, float duy, float duz,
    float sf, int& cell, float& fx, float& fy, float& fz)
{
    float ux = fminf(fmaxf(fmaf(sf, dux, u0x), 0.0f), 127.0f);
    float uy = fminf(fmaxf(fmaf(sf, duy, u0y), 0.0f), 127.0f);
    float uz = fminf(fmaxf(fmaf(sf, duz, u0z), 0.0f), 127.0f);
    float cx = fminf(floorf(ux), 126.0f);
    float cy = fminf(floorf(uy), 126.0f);
    float cz = fminf(floorf(uz), 126.0f);
    fx = ux - cx; fy = uy - cy; fz = uz - cz;
    cell = ((int)cy << 14) + ((int)cz << 7) + (int)cx;
}

// 22-bit path key: [entry_y5 entry_x5 | exit_x4 exit_y4 exit_z4]
__device__ __forceinline__ int pathKey22(
    float ox, float oy, float oz, float dx, float dy, float dz,
    float near_, float far_)
{
    float exw = fmaf(near_, dx, ox), eyw = fmaf(near_, dy, oy);
    int ex = min(31, max(0, (int)((exw - kBminX) * 16.0f)));
    int ey = min(31, max(0, (int)((eyw - kBminY) * 32.0f)));
    float xx = fmaf(far_, dx, ox), xy = fmaf(far_, dy, oy), xz = fmaf(far_, dz, oz);
    int qx = min(15, max(0, (int)((xx - kBminX) * 8.0f)));
    int qy = min(15, max(0, (int)((xy - kBminY) * 16.0f)));
    int qz = min(15, max(0, (int)((xz - kBminZ) * 8.0f)));
    return (((ey << 5) | ex) << 12) | (qx << 8) | (qy << 4) | qz;
}

// ---------------- fat kernel: repack || hist ------------------------------
__device__ __forceinline__ unsigned packvox8(
    const float* __restrict__ sig, const float* __restrict__ rgb, int idx)
{
    unsigned s = (unsigned)__float2int_rn(fminf(fmaxf(sig[idx], 0.f), 1.f) * 255.f);
    unsigned r = (unsigned)__float2int_rn(fminf(fmaxf(rgb[3*idx+0], 0.f), 1.f) * 255.f);
    unsigned g = (unsigned)__float2int_rn(fminf(fmaxf(rgb[3*idx+1], 0.f), 1.f) * 255.f);
    unsigned b = (unsigned)__float2int_rn(fminf(fmaxf(rgb[3*idx+2], 0.f), 1.f) * 255.f);
    return s | (r << 8) | (g << 16) | (b << 24);
}

// blocks [0, 16384): corner-major u8 repack into X-FASTEST layout.
//   block=(ix, iy0); thread z: cell corners byte0=(y0,z0) byte1=(y0,z1)
//   byte2=(y1,z0) byte3=(y1,z1) per channel; write to (iy0<<14)+(z<<7)+ix.
// blocks [16384, 18432): 22-bit key histogram.
__global__ __launch_bounds__(128) void fat_k(
    const float* __restrict__ sig, const float* __restrict__ rgb,
    uint4* __restrict__ gout,
    const float* __restrict__ rays_o, const float* __restrict__ rays_d,
    int* __restrict__ hist)
{
    int bid = blockIdx.x;
    if (bid < kG * kG) {
        __shared__ unsigned row[2][kG];
        int ix  = bid >> 7;
        int iy0 = bid & 127;
        int iy1 = min(iy0 + 1, 127);
        int z   = threadIdx.x;
        row[0][z] = packvox8(sig, rgb, (ix << 14) + (iy0 << 7) + z);
        row[1][z] = packvox8(sig, rgb, (ix << 14) + (iy1 << 7) + z);
        __syncthreads();
        int z1 = min(z + 1, 127);
        unsigned a = row[0][z], b = row[0][z1], c = row[1][z], d = row[1][z1];
        uint4 cell;
        cell.x = ( a        & 0xffu)        | (( b        & 0xffu) << 8)
               | ((c        & 0xffu) << 16) | (( d        & 0xffu) << 24);
        cell.y = ((a >>  8) & 0xffu)        | (((b >>  8) & 0xffu) << 8)
               | (((c >> 8) & 0xffu) << 16) | (((d >>  8) & 0xffu) << 24);
        cell.z = ((a >> 16) & 0xffu)        | (((b >> 16) & 0xffu) << 8)
               | (((c >> 16) & 0xffu) << 16)| (((d >> 16) & 0xffu) << 24);
        cell.w = ( a >> 24)                 | (( b >> 24) << 8)
               | ((c >> 24) << 16)          | (( d >> 24) << 24);
        gout[(iy0 << 14) + (z << 7) + ix] = cell;      // x-fastest
    } else {
        int i = (bid - kG * kG) * 128 + (int)threadIdx.x;
        if (i >= kNRays) return;
        float ox = rays_o[3*i+0], oy = rays_o[3*i+1], oz = rays_o[3*i+2];
        float dx = rays_d[3*i+0], dy = rays_d[3*i+1], dz = rays_d[3*i+2];
        float near_, far_;
        slabNearFar(ox, oy, oz, dx, dy, dz, near_, far_);
        atomicAdd(&hist[pathKey22(ox, oy, oz, dx, dy, dz, near_, far_)], 1);
    }
}

// ---------------- hierarchical scan ---------------------------------------
__global__ __launch_bounds__(256) void scan_blk_k(
    int* __restrict__ h, int* __restrict__ bsum)
{
    __shared__ int tmp[256];
    int t = threadIdx.x;
    int i = blockIdx.x * 256 + t;
    int v = h[i];
    tmp[t] = v;
    __syncthreads();
    int x = v;
    for (int off = 1; off < 256; off <<= 1) {
        int y = (t >= off) ? tmp[t - off] : 0;
        __syncthreads();
        x += y;
        tmp[t] = x;
        __syncthreads();
    }
    h[i] = x - v;
    if (t == 255) bsum[blockIdx.x] = x;
}

__global__ __launch_bounds__(64) void scan_top64_k(int* __restrict__ b)
{
    int t = threadIdx.x;
    int v = b[t];
    int x = v;
    for (int off = 1; off < 64; off <<= 1) {
        int y = __shfl_up(x, off);
        if (t >= off) x += y;
    }
    b[t] = x - v;
}

__global__ __launch_bounds__(256) void scatter22_k(
    const float* __restrict__ rays_o, const float* __restrict__ rays_d,
    int* __restrict__ h, const int* __restrict__ bsum,
    const int* __restrict__ bsum2, int* __restrict__ perm,
    float4* __restrict__ so4, float4* __restrict__ sd4)
{
    int i = blockIdx.x * 256 + threadIdx.x;
    if (i >= kNRays) return;
    float ox = rays_o[3*i+0], oy = rays_o[3*i+1], oz = rays_o[3*i+2];
    float dx = rays_d[3*i+0], dy = rays_d[3*i+1], dz = rays_d[3*i+2];
    float near_, far_;
    slabNearFar(ox, oy, oz, dx, dy, dz, near_, far_);
    int key = pathKey22(ox, oy, oz, dx, dy, dz, near_, far_);
    float dt = (far_ - near_) * (1.0f / (float)kSteps);
    int pos = bsum2[key >> 16] + bsum[key >> 8] + atomicAdd(&h[key], 1);
    perm[pos] = i;
    so4[pos] = make_float4(ox, oy, oz, near_);
    sd4[pos] = make_float4(dx, dy, dz, dt);
}

// ---------------- fused render + merge ------------------------------------
__global__ __launch_bounds__(512, 8) void render_f_k(
    const float4* __restrict__ so4, const float4* __restrict__ sd4,
    const uint4* __restrict__ grid, const int* __restrict__ perm,
    const float* __restrict__ bg, float* __restrict__ out)
{
    __shared__ float4 part[256];

    int bid = blockIdx.x;                      // 1024 blocks
    int swz = (bid & 7) * 128 + (bid >> 3);    // bijective XCD chunk swizzle
    int t    = (int)threadIdx.x;
    int rloc = t & 255;
    int seg  = t >> 8;
    int sj   = swz * 256 + rloc;               // sorted ray index

    float4 o4 = so4[sj], d4 = sd4[sj];
    float ox = o4.x, oy = o4.y, oz = o4.z, near_ = o4.w;
    float dx = d4.x, dy = d4.y, dz = d4.z, dt = d4.w;
    float dtq = dt * kInvScale;

    const int nsteps = kSteps / 2;

    float t0  = fmaf(0.5f, dt, near_);
    float u0x = (fmaf(t0, dx, ox) - kBminX) * kSx;
    float u0y = (fmaf(t0, dy, oy) - kBminY) * kSy;
    float u0z = (fmaf(t0, dz, oz) - kBminZ) * kSz;
    float dux = dx * dt * kSx, duy = dy * dt * kSy, duz = dz * dt * kSz;
    float sb = (float)(seg * nsteps);
    u0x = fmaf(sb, dux, u0x); u0y = fmaf(sb, duy, u0y); u0z = fmaf(sb, duz, u0z);

    int c;
    float f0x, f0y, f0z, f1x, f1y, f1z, f2x, f2y, f2z;
    cellOf(u0x, u0y, u0z, dux, duy, duz, 0.0f, c, f0x, f0y, f0z);
    uint4 q0 = grid[c], q1 = grid[c + 1];
    cellOf(u0x, u0y, u0z, dux, duy, duz, 1.0f, c, f1x, f1y, f1z);
    uint4 m0 = grid[c], m1 = grid[c + 1];

    float T = 1.0f, wsum = 0.0f, ar = 0.0f, ag = 0.0f, ab = 0.0f;

    for (int s = 0; s < nsteps; ++s) {
        float sn = (float)min(s + 2, nsteps - 1);
        cellOf(u0x, u0y, u0z, dux, duy, duz, sn, c, f2x, f2y, f2z);
        uint4 n0 = grid[c], n1 = grid[c + 1];

        float wz0 = 1.0f - f0z, wy0 = 1.0f - f0y;
        float sA, sB, rA, rB, gA, gB, bA, bB;
#if USE_UDOT4
        int w00 = __float2int_rn(wy0 * wz0 * 255.0f);
        int w01 = __float2int_rn(wy0 * f0z * 255.0f);
        int w10 = __float2int_rn(f0y * wz0 * 255.0f);
        int w11 = 255 - w00 - w01 - w10;
        w11 = max(w11, 0);
        unsigned wp = (unsigned)(w00 | (w01 << 8) | (w10 << 16) | (w11 << 24));
        sA = (float)__builtin_amdgcn_udot4(q0.x, wp, 0u, false);
        rA = (float)__builtin_amdgcn_udot4(q0.y, wp, 0u, false);
        gA = (float)__builtin_amdgcn_udot4(q0.z, wp, 0u, false);
        bA = (float)__builtin_amdgcn_udot4(q0.w, wp, 0u, false);
        sB = (float)__builtin_amdgcn_udot4(q1.x, wp, 0u, false);
        rB = (float)__builtin_amdgcn_udot4(q1.y, wp, 0u, false);
        gB = (float)__builtin_amdgcn_udot4(q1.z, wp, 0u, false);
        bB = (float)__builtin_amdgcn_udot4(q1.w, wp, 0u, false);
#else
        float w00 = wy0 * wz0, w01 = wy0 * f0z, w10 = f0y * wz0, w11 = f0y * f0z;
        #define CB0(u) ((float)((u) & 0xffu))
        #define CB1(u) ((float)(((u) >> 8) & 0xffu))
        #define CB2(u) ((float)(((u) >> 16) & 0xffu))
        #define CB3(u) ((float)((u) >> 24))
        sA = w00*CB0(q0.x) + w01*CB1(q0.x) + w10*CB2(q0.x) + w11*CB3(q0.x);
        rA = w00*CB0(q0.y) + w01*CB1(q0.y) + w10*CB2(q0.y) + w11*CB3(q0.y);
        gA = w00*CB0(q0.z) + w01*CB1(q0.z) + w10*CB2(q0.z) + w11*CB3(q0.z);
        bA = w00*CB0(q0.w) + w01*CB1(q0.w) + w10*CB2(q0.w) + w11*CB3(q0.w);
        sB = w00*CB0(q1.x) + w01*CB1(q1.x) + w10*CB2(q1.x) + w11*CB3(q1.x);
        rB = w00*CB0(q1.y) + w01*CB1(q1.y) + w10*CB2(q1.y) + w11*CB3(q1.y);
        gB = w00*CB0(q1.z) + w01*CB1(q1.z) + w10*CB2(q1.z) + w11*CB3(q1.z);
        bB = w00*CB0(q1.w) + w01*CB1(q1.w) + w10*CB2(q1.w) + w11*CB3(q1.w);
#endif
        float sv = fmaf(f0x, sB - sA, sA);      // raw kScale units
        float rv = fmaf(f0x, rB - rA, rA);
        float gv = fmaf(f0x, gB - gA, gA);
        float bv = fmaf(f0x, bB - bA, bA);

        float sigr  = (sv > kSigThr) ? sv : 0.0f;          // sigma > 0.01
        float alpha = 1.0f - __expf(-sigr * dtq);
        alpha = (T > kTTh) ? alpha : 0.0f;                  // reference gating
        float w = alpha * T;
        T *= (1.0f - alpha);
        wsum += w;
        ar = fmaf(w, rv, ar);
        ag = fmaf(w, gv, ag);
        ab = fmaf(w, bv, ab);

        q0 = m0; q1 = m1; m0 = n0; m1 = n1;
        f0x = f1x; f0y = f1y; f0z = f1z;
        f1x = f2x; f1y = f2y; f1z = f2z;
    }

    if (seg == 1) part[rloc] = make_float4(ar, ag, ab, wsum);
    __syncthreads();
    if (seg == 0) {
        float4 b = part[rloc];
        ar = fmaf(T, b.x, ar);
        ag = fmaf(T, b.y, ag);
        ab = fmaf(T, b.z, ab);
        float ws = fmaf(T, b.w, wsum);
        int ray = perm[sj];
        float omw = 1.0f - ws;
        out[3 * ray + 0] = fminf(fmaxf(fmaf(omw, bg[0], ar * kInvScale), 0.0f), 1.0f);
        out[3 * ray + 1] = fminf(fmaxf(fmaf(omw, bg[1], ag * kInvScale), 0.0f), 1.0f);
        out[3 * ray + 2] = fminf(fmaxf(fmaf(omw, bg[2], ab * kInvScale), 0.0f), 1.0f);
    }
}

// ---------------- plain fallback ------------------------------------------
__global__ __launch_bounds__(256) void render_plain_k(
    const float* __restrict__ rays_o, const float* __restrict__ rays_d,
    const float* __restrict__ sgrid, const float* __restrict__ cgrid,
    const float* __restrict__ bg, float* __restrict__ out)
{
    int i = blockIdx.x * 256 + threadIdx.x;
    if (i >= kNRays) return;
    float ox = rays_o[3*i+0], oy = rays_o[3*i+1], oz = rays_o[3*i+2];
    float dx = rays_d[3*i+0], dy = rays_d[3*i+1], dz = rays_d[3*i+2];
    float near_, far_;
    slabNearFar(ox, oy, oz, dx, dy, dz, near_, far_);
    float dt = (far_ - near_) * (1.0f / (float)kSteps);
    float t0  = fmaf(0.5f, dt, near_);
    float u0x = (fmaf(t0, dx, ox) - kBminX) * kSx;
    float u0y = (fmaf(t0, dy, oy) - kBminY) * kSy;
    float u0z = (fmaf(t0, dz, oz) - kBminZ) * kSz;
    float dux = dx * dt * kSx, duy = dy * dt * kSy, duz = dz * dt * kSz;
    float T = 1.0f, wsum = 0.0f, accr = 0.0f, accg = 0.0f, accb = 0.0f;
    for (int s = 0; s < kSteps; ++s) {
        float ux = fminf(fmaxf(fmaf((float)s, dux, u0x), 0.0f), 127.0f);
        float uy = fminf(fmaxf(fmaf((float)s, duy, u0y), 0.0f), 127.0f);
        float uz = fminf(fmaxf(fmaf((float)s, duz, u0z), 0.0f), 127.0f);
        float cx = fminf(floorf(ux), 126.0f);
        float cy = fminf(floorf(uy), 126.0f);
        float cz = fminf(floorf(uz), 126.0f);
        float fx = ux - cx, fy = uy - cy, fz = uz - cz;
        int base = ((int)cx << 14) + ((int)cy << 7) + (int)cz;
        float w0x = 1.0f - fx, w0y = 1.0f - fy, w0z = 1.0f - fz;
        float wa = w0x*w0y*w0z, wb = w0x*w0y*fz, wc = w0x*fy*w0z, wd = w0x*fy*fz;
        float we = fx*w0y*w0z,  wf = fx*w0y*fz,  wg = fx*fy*w0z,  wh = fx*fy*fz;
        int i000 = base, i001 = base + 1, i010 = base + kG, i011 = base + kG + 1;
        int i100 = base + kG*kG, i101 = i100 + 1, i110 = i100 + kG, i111 = i110 + 1;
        float sv = wa*sgrid[i000] + wb*sgrid[i001] + wc*sgrid[i010] + wd*sgrid[i011]
                 + we*sgrid[i100] + wf*sgrid[i101] + wg*sgrid[i110] + wh*sgrid[i111];
        float rv = wa*cgrid[3*i000+0] + wb*cgrid[3*i001+0] + wc*cgrid[3*i010+0] + wd*cgrid[3*i011+0]
                 + we*cgrid[3*i100+0] + wf*cgrid[3*i101+0] + wg*cgrid[3*i110+0] + wh*cgrid[3*i111+0];
        float gv = wa*cgrid[3*i000+1] + wb*cgrid[3*i001+1] + wc*cgrid[3*i010+1] + wd*cgrid[3*i011+1]
                 + we*cgrid[3*i100+1] + wf*cgrid[3*i101+1] + wg*cgrid[3*i110+1] + wh*cgrid[3*i111+1];
        float bv = wa*cgrid[3*i000+2] + wb*cgrid[3*i001+2] + wc*cgrid[3*i010+2] + wd*cgrid[3*i011+2]
                 + we*cgrid[3*i100+2] + wf*cgrid[3*i101+2] + wg*cgrid[3*i110+2] + wh*cgrid[3*i111+2];
        float sig = (sv > 0.01f) ? sv : 0.0f;
        float alpha = 1.0f - __expf(-sig * dt);
        float w = alpha * T;
        T *= (1.0f - alpha);
        wsum += w;
        accr = fmaf(w, rv, accr); accg = fmaf(w, gv, accg); accb = fmaf(w, bv, accb);
        if (T <= kTTh) break;
    }
    float omw = 1.0f - wsum;
    out[3 * i + 0] = fminf(fmaxf(fmaf(omw, bg[0], accr), 0.0f), 1.0f);
    out[3 * i + 1] = fminf(fmaxf(fmaf(omw, bg[1], accg), 0.0f), 1.0f);
    out[3 * i + 2] = fminf(fmaxf(fmaf(omw, bg[2], accb), 0.0f), 1.0f);
}

extern "C" void kernel_launch(void* const* d_in, const int* in_sizes, int n_in,
                              void* d_out, int out_size, void* d_ws, size_t ws_size,
                              hipStream_t stream)
{
    const float* rays_o = (const float*)d_in[0];
    const float* rays_d = (const float*)d_in[1];
    const float* sgrid  = (const float*)d_in[2];
    const float* cgrid  = (const float*)d_in[3];
    const float* bg     = (const float*)d_in[4];
    float* out = (float*)d_out;

    const int RB_BLK = kNRays / 256;   // 1024

    // grid 32MiB | hist 16MiB | bsum 64KiB | bsum2 256B | perm 1MiB
    // | so4 4MiB | sd4 4MiB  ~= 57.1 MiB
    size_t a_grid  = 0;
    size_t a_hist  = a_grid  + (size_t)kG3 * sizeof(uint4);
    size_t a_bsum  = a_hist  + (size_t)kKB * sizeof(int);
    size_t a_bsum2 = a_bsum  + (size_t)(kKB / 256) * sizeof(int);
    size_t a_perm  = a_bsum2 + (size_t)64 * sizeof(int);
    size_t a_so4   = a_perm  + (size_t)kNRays * sizeof(int);
    size_t a_sd4   = a_so4   + (size_t)kNRays * sizeof(float4);
    size_t needA   = a_sd4   + (size_t)kNRays * sizeof(float4);

    if (ws_size >= needA) {
        char* ws = (char*)d_ws;
        uint4*  grid  = (uint4*)(ws + a_grid);
        int*    hist  = (int*)(ws + a_hist);
        int*    bsum  = (int*)(ws + a_bsum);
        int*    bsum2 = (int*)(ws + a_bsum2);
        int*    perm  = (int*)(ws + a_perm);
        float4* so4   = (float4*)(ws + a_so4);
        float4* sd4   = (float4*)(ws + a_sd4);

        hipMemsetAsync(hist, 0, (size_t)kKB * sizeof(int), stream);
        fat_k<<<kG * kG + kNRays / 128, 128, 0, stream>>>(
            sgrid, cgrid, grid, rays_o, rays_d, hist);
        scan_blk_k<<<kKB / 256, 256, 0, stream>>>(hist, bsum);
        scan_blk_k<<<kKB / 65536, 256, 0, stream>>>(bsum, bsum2);
        scan_top64_k<<<1, 64, 0, stream>>>(bsum2);
        scatter22_k<<<RB_BLK, 256, 0, stream>>>(rays_o, rays_d, hist, bsum,
                                                bsum2, perm, so4, sd4);
        render_f_k<<<kNRays / 256, 512, 0, stream>>>(so4, sd4, grid, perm, bg, out);
    } else {
        render_plain_k<<<RB_BLK, 256, 0, stream>>>(
            rays_o, rays_d, sgrid, cgrid, bg, out);
    }
}